// Round 2
// baseline (2156.351 us; speedup 1.0000x reference)
//
#include <hip/hip_runtime.h>
#include <math.h>

// ---- problem constants ----
#define N_NODES 33
#define SEQ 24
#define BATCH 64
#define G_GRAPHS (BATCH * SEQ)          // 1536
#define EPG 64
#define E_EDGES (G_GRAPHS * EPG)        // 98304
#define N_TOTAL (G_GRAPHS * N_NODES)    // 50688
#define HID 64
#define HEADS 8
#define HC (HID * HEADS)                // 512
#define LSTM1_H 128
#define LSTM2_H 64
#define NEG_SLOPE 0.2f

// graph chunking to keep d_ws footprint small (ws_size is harness-chosen;
// round-0's 330 MB layout aborted with a memory fault — suspected overflow)
#define N_CHUNKS 4
#define CHUNK_G (G_GRAPHS / N_CHUNKS)   // 384 graphs
#define CHUNK_N (CHUNK_G * N_NODES)     // 12672 nodes

__device__ __forceinline__ float sigmoidf_(float x) { return 1.f / (1.f + expf(-x)); }
__device__ __forceinline__ float eluf_(float x) { return x > 0.f ? x : expm1f(x); }
__device__ __forceinline__ float lreluf_(float x) { return x > 0.f ? x : NEG_SLOPE * x; }

// ============================================================
// GAT layer 1 for one chunk: block b handles graph g0+b, writes h1c rows
// at LOCAL offset b*33.
// ============================================================
__global__ __launch_bounds__(256) void gat1_kernel(
    const float* __restrict__ x, const int* __restrict__ src, const int* __restrict__ dst,
    const float* __restrict__ ea, const float* __restrict__ Wl, const float* __restrict__ Wr,
    const float* __restrict__ We, const float* __restrict__ att, const float* __restrict__ bias,
    float* __restrict__ h1c, int g0) {
  __shared__ float Wl_s[2 * 512], Wr_s[2 * 512], We_s[3 * 512], att_s[512];
  __shared__ float xs[N_NODES][2], eas[EPG][3];
  __shared__ float logit[EPG][HEADS];   // later overwritten with alpha
  __shared__ int sloc[EPG], dloc[EPG], deg[N_NODES], start[N_NODES], fill[N_NODES], elist[EPG];

  const int g = g0 + blockIdx.x, tid = threadIdx.x;
  const int nb = g * N_NODES, eb = g * EPG;
  const int lb = blockIdx.x * N_NODES;      // local row base in h1c

  for (int i = tid; i < 1024; i += 256) { Wl_s[i] = Wl[i]; Wr_s[i] = Wr[i]; }
  for (int i = tid; i < 1536; i += 256) We_s[i] = We[i];
  for (int i = tid; i < 512; i += 256) att_s[i] = att[i];
  if (tid < 66) ((float*)xs)[tid] = x[nb * 2 + tid];
  for (int i = tid; i < EPG * 3; i += 256) ((float*)eas)[i] = ea[eb * 3 + i];
  if (tid < EPG) { sloc[tid] = src[eb + tid] - nb; dloc[tid] = dst[eb + tid] - nb; }
  if (tid < N_NODES) { deg[tid] = 0; fill[tid] = 0; }
  __syncthreads();
  if (tid < EPG) atomicAdd(&deg[dloc[tid]], 1);
  __syncthreads();
  if (tid == 0) { int a = 0; for (int n = 0; n < N_NODES; ++n) { start[n] = a; a += deg[n]; } }
  __syncthreads();
  if (tid < EPG) { int d = dloc[tid]; int p = atomicAdd(&fill[d], 1); elist[start[d] + p] = tid; }

  // logits: one task per (edge, head)
  for (int t = tid; t < EPG * HEADS; t += 256) {
    int e = t >> 3, h = t & 7;
    int s = sloc[e], d = dloc[e];
    float xs0 = xs[s][0], xs1 = xs[s][1], xd0 = xs[d][0], xd1 = xs[d][1];
    float e0 = eas[e][0], e1 = eas[e][1], e2 = eas[e][2];
    float acc = 0.f;
    int base = h * 64;
    #pragma unroll 8
    for (int c = 0; c < 64; ++c) {
      int j = base + c;
      float v = xs0 * Wl_s[j] + xs1 * Wl_s[512 + j]
              + xd0 * Wr_s[j] + xd1 * Wr_s[512 + j]
              + e0 * We_s[j] + e1 * We_s[512 + j] + e2 * We_s[1024 + j];
      acc += lreluf_(v) * att_s[j];
    }
    logit[e][h] = acc;
  }
  __syncthreads();

  // segment softmax per (dst node, head); alpha overwrites logit in place
  for (int t = tid; t < N_NODES * HEADS; t += 256) {
    int n = t >> 3, h = t & 7;
    int s0 = start[n], dn = deg[n];
    float mx = -1e30f;
    for (int i = 0; i < dn; ++i) mx = fmaxf(mx, logit[elist[s0 + i]][h]);
    float den = 0.f;
    for (int i = 0; i < dn; ++i) den += expf(logit[elist[s0 + i]][h] - mx);
    float inv = 1.f / (den + 1e-16f);
    for (int i = 0; i < dn; ++i) {
      int e = elist[s0 + i];
      logit[e][h] = expf(logit[e][h] - mx) * inv;
    }
  }
  __syncthreads();

  // aggregate: out[n][j] = sum_{e->n} alpha[e][h] * xl[src(e)][j]; + bias; ELU
  for (int t = tid; t < N_NODES * HC; t += 256) {
    int n = t >> 9, j = t & 511, h = j >> 6;
    int s0 = start[n], dn = deg[n];
    float acc = 0.f;
    for (int i = 0; i < dn; ++i) {
      int e = elist[s0 + i]; int s = sloc[e];
      float xlv = xs[s][0] * Wl_s[j] + xs[s][1] * Wl_s[512 + j];
      acc += logit[e][h] * xlv;
    }
    acc += bias[j];
    h1c[(size_t)(lb + n) * HC + j] = eluf_(acc);
  }
}

// ============================================================
// fp32 GEMM  C[M,N] = A[M,K] @ B[K,N]   (row-major, M%64==0, N%64==0, K%16==0)
// ============================================================
__global__ __launch_bounds__(256) void gemm_nn(
    const float* __restrict__ A, const float* __restrict__ B, float* __restrict__ C,
    int M, int N, int K) {
  __shared__ float As[64][17];   // [m][k], padded
  __shared__ float Bs[16][64];   // [k][n]
  const int bm = blockIdx.y * 64;
  const int bn = blockIdx.x * 64;
  const int tid = threadIdx.x;
  const int tr = tid >> 4;       // 0..15 (m)
  const int tc = tid & 15;       // 0..15 (n)
  float acc[4][4] = {};
  for (int k0 = 0; k0 < K; k0 += 16) {
    for (int i = tid; i < 64 * 16; i += 256) {
      int m = i >> 4, kk = i & 15;
      As[m][kk] = A[(size_t)(bm + m) * K + k0 + kk];
    }
    for (int i = tid; i < 16 * 64; i += 256) {
      int kk = i >> 6, n = i & 63;
      Bs[kk][n] = B[(size_t)(k0 + kk) * N + bn + n];
    }
    __syncthreads();
    #pragma unroll
    for (int kk = 0; kk < 16; ++kk) {
      float a[4], b[4];
      #pragma unroll
      for (int u = 0; u < 4; ++u) a[u] = As[tr * 4 + u][kk];
      #pragma unroll
      for (int v = 0; v < 4; ++v) b[v] = Bs[kk][tc * 4 + v];
      #pragma unroll
      for (int u = 0; u < 4; ++u)
        #pragma unroll
        for (int v = 0; v < 4; ++v)
          acc[u][v] += a[u] * b[v];
    }
    __syncthreads();
  }
  #pragma unroll
  for (int u = 0; u < 4; ++u)
    #pragma unroll
    for (int v = 0; v < 4; ++v)
      C[(size_t)(bm + tr * 4 + u) * N + bn + tc * 4 + v] = acc[u][v];
}

// ============================================================
// fp32 GEMM  C[M,N] = A[M,K] @ B[N,K]^T + bias1[n] + bias2[n]
// ============================================================
__global__ __launch_bounds__(256) void gemm_abt_bias(
    const float* __restrict__ A, const float* __restrict__ B,
    const float* __restrict__ bias1, const float* __restrict__ bias2,
    float* __restrict__ C, int M, int N, int K) {
  __shared__ float As[64][17];
  __shared__ float Bs[64][17];
  const int bm = blockIdx.y * 64;
  const int bn = blockIdx.x * 64;
  const int tid = threadIdx.x;
  const int tr = tid >> 4;
  const int tc = tid & 15;
  float acc[4][4] = {};
  for (int k0 = 0; k0 < K; k0 += 16) {
    for (int i = tid; i < 64 * 16; i += 256) {
      int m = i >> 4, kk = i & 15;
      As[m][kk] = A[(size_t)(bm + m) * K + k0 + kk];
      Bs[m][kk] = B[(size_t)(bn + m) * K + k0 + kk];
    }
    __syncthreads();
    #pragma unroll
    for (int kk = 0; kk < 16; ++kk) {
      float a[4], b[4];
      #pragma unroll
      for (int u = 0; u < 4; ++u) a[u] = As[tr * 4 + u][kk];
      #pragma unroll
      for (int v = 0; v < 4; ++v) b[v] = Bs[tc * 4 + v][kk];
      #pragma unroll
      for (int u = 0; u < 4; ++u)
        #pragma unroll
        for (int v = 0; v < 4; ++v)
          acc[u][v] += a[u] * b[v];
    }
    __syncthreads();
  }
  #pragma unroll
  for (int u = 0; u < 4; ++u)
    #pragma unroll
    for (int v = 0; v < 4; ++v) {
      int j = bn + tc * 4 + v;
      C[(size_t)(bm + tr * 4 + u) * N + j] = acc[u][v] + bias1[j] + bias2[j];
    }
}

// ============================================================
// GAT layer 2 for one chunk: block b handles graph g0+b. xl2c/xr2c rows are
// LOCAL (b*33+...); h2 rows are GLOBAL ((g0+b)*33+...).
// ============================================================
__global__ __launch_bounds__(256) void gat2_kernel(
    const float* __restrict__ xl2c, const float* __restrict__ xr2c,
    const int* __restrict__ src, const int* __restrict__ dst,
    const float* __restrict__ ea, const float* __restrict__ We,
    const float* __restrict__ att, const float* __restrict__ bias,
    float* __restrict__ h2, int g0) {
  __shared__ float We_s[3 * 512], att_s[512], b_s[HID];
  __shared__ float eas[EPG][3], logit[EPG][HEADS];
  __shared__ int sloc[EPG], dloc[EPG], deg[N_NODES], start[N_NODES], fill[N_NODES], elist[EPG];

  const int g = g0 + blockIdx.x, tid = threadIdx.x;
  const int nb = g * N_NODES, eb = g * EPG;
  const int lb = blockIdx.x * N_NODES;      // local row base in xl2c/xr2c

  for (int i = tid; i < 1536; i += 256) We_s[i] = We[i];
  for (int i = tid; i < 512; i += 256) att_s[i] = att[i];
  if (tid < HID) b_s[tid] = bias[tid];
  for (int i = tid; i < EPG * 3; i += 256) ((float*)eas)[i] = ea[eb * 3 + i];
  if (tid < EPG) { sloc[tid] = src[eb + tid] - nb; dloc[tid] = dst[eb + tid] - nb; }
  if (tid < N_NODES) { deg[tid] = 0; fill[tid] = 0; }
  __syncthreads();
  if (tid < EPG) atomicAdd(&deg[dloc[tid]], 1);
  __syncthreads();
  if (tid == 0) { int a = 0; for (int n = 0; n < N_NODES; ++n) { start[n] = a; a += deg[n]; } }
  __syncthreads();
  if (tid < EPG) { int d = dloc[tid]; int p = atomicAdd(&fill[d], 1); elist[start[d] + p] = tid; }

  for (int t = tid; t < EPG * HEADS; t += 256) {
    int e = t >> 3, h = t & 7;
    const float* xl = xl2c + (size_t)(lb + sloc[e]) * HC + h * 64;
    const float* xr = xr2c + (size_t)(lb + dloc[e]) * HC + h * 64;
    float e0 = eas[e][0], e1 = eas[e][1], e2 = eas[e][2];
    float acc = 0.f;
    int base = h * 64;
    #pragma unroll 8
    for (int c = 0; c < 64; ++c) {
      int j = base + c;
      float v = xl[c] + xr[c] + e0 * We_s[j] + e1 * We_s[512 + j] + e2 * We_s[1024 + j];
      acc += lreluf_(v) * att_s[j];
    }
    logit[e][h] = acc;
  }
  __syncthreads();

  for (int t = tid; t < N_NODES * HEADS; t += 256) {
    int n = t >> 3, h = t & 7;
    int s0 = start[n], dn = deg[n];
    float mx = -1e30f;
    for (int i = 0; i < dn; ++i) mx = fmaxf(mx, logit[elist[s0 + i]][h]);
    float den = 0.f;
    for (int i = 0; i < dn; ++i) den += expf(logit[elist[s0 + i]][h] - mx);
    float inv = 1.f / (den + 1e-16f);
    for (int i = 0; i < dn; ++i) {
      int e = elist[s0 + i];
      logit[e][h] = expf(logit[e][h] - mx) * inv;
    }
  }
  __syncthreads();

  // out[n][c] = mean_h sum_{e->n} alpha[e][h] * xl2[src][h*64+c]; + bias; ELU
  for (int t = tid; t < N_NODES * HID; t += 256) {
    int n = t >> 6, c = t & 63;
    int s0 = start[n], dn = deg[n];
    float acc = 0.f;
    for (int i = 0; i < dn; ++i) {
      int e = elist[s0 + i];
      const float* xl = xl2c + (size_t)(lb + sloc[e]) * HC + c;
      #pragma unroll
      for (int h = 0; h < HEADS; ++h) acc += logit[e][h] * xl[h * 64];
    }
    acc = acc * 0.125f + b_s[c];
    h2[(size_t)(nb + n) * HID + c] = eluf_(acc);
  }
}

// ============================================================
// LSTM1 recurrence: one workgroup per batch row, 512 threads = 512 gate elems.
// X already contains xt@Wih^T + bih + bhh for all timesteps.
// ============================================================
__global__ __launch_bounds__(512, 2) void lstm1_kernel(
    const float* __restrict__ X, const float* __restrict__ Whh, float* __restrict__ Y) {
  __shared__ float hs[LSTM1_H], cs[LSTM1_H], gs[4 * LSTM1_H];
  const int b = blockIdx.x, j = threadIdx.x;
  float4 w[32];
  const float4* wp = (const float4*)(Whh + (size_t)j * LSTM1_H);
  #pragma unroll
  for (int q = 0; q < 32; ++q) w[q] = wp[q];
  if (j < LSTM1_H) { hs[j] = 0.f; cs[j] = 0.f; }
  __syncthreads();
  for (int t = 0; t < SEQ; ++t) {
    float acc = X[((size_t)b * SEQ + t) * 512 + j];
    #pragma unroll
    for (int q = 0; q < 32; ++q) {
      acc += w[q].x * hs[4 * q] + w[q].y * hs[4 * q + 1]
           + w[q].z * hs[4 * q + 2] + w[q].w * hs[4 * q + 3];
    }
    gs[j] = acc;
    __syncthreads();
    if (j < LSTM1_H) {
      float ig = sigmoidf_(gs[j]);
      float fg = sigmoidf_(gs[LSTM1_H + j]);
      float gg = tanhf(gs[2 * LSTM1_H + j]);
      float og = sigmoidf_(gs[3 * LSTM1_H + j]);
      float c = fg * cs[j] + ig * gg;
      cs[j] = c;
      float h = og * tanhf(c);
      hs[j] = h;
      Y[((size_t)b * SEQ + t) * LSTM1_H + j] = h;
    }
    __syncthreads();
  }
}

// ============================================================
// LSTM2 input projection: X2[g][j] = Y1[g] . Wih2[j] + bih[j] + bhh[j]
// ============================================================
__global__ __launch_bounds__(256) void x2_kernel(
    const float* __restrict__ Y1, const float* __restrict__ Wih,
    const float* __restrict__ bih, const float* __restrict__ bhh,
    float* __restrict__ X2) {
  __shared__ float ys[LSTM1_H];
  const int g = blockIdx.x, j = threadIdx.x;
  if (j < LSTM1_H) ys[j] = Y1[(size_t)g * LSTM1_H + j];
  __syncthreads();
  const float4* wp = (const float4*)(Wih + (size_t)j * LSTM1_H);
  float acc = bih[j] + bhh[j];
  #pragma unroll
  for (int q = 0; q < 32; ++q) {
    float4 w = wp[q];
    acc += w.x * ys[4 * q] + w.y * ys[4 * q + 1] + w.z * ys[4 * q + 2] + w.w * ys[4 * q + 3];
  }
  X2[(size_t)g * 256 + j] = acc;
}

// ============================================================
// LSTM2 recurrence + final FC (only h at t=SEQ-1 is needed downstream)
// ============================================================
__global__ __launch_bounds__(256, 2) void lstm2_fc_kernel(
    const float* __restrict__ X, const float* __restrict__ Whh,
    const float* __restrict__ fcW, const float* __restrict__ fcb,
    float* __restrict__ out) {
  __shared__ float hs[LSTM2_H], cs[LSTM2_H], gs[4 * LSTM2_H];
  const int b = blockIdx.x, j = threadIdx.x;
  float4 w[16];
  const float4* wp = (const float4*)(Whh + (size_t)j * LSTM2_H);
  #pragma unroll
  for (int q = 0; q < 16; ++q) w[q] = wp[q];
  if (j < LSTM2_H) { hs[j] = 0.f; cs[j] = 0.f; }
  __syncthreads();
  for (int t = 0; t < SEQ; ++t) {
    float acc = X[((size_t)b * SEQ + t) * 256 + j];
    #pragma unroll
    for (int q = 0; q < 16; ++q) {
      acc += w[q].x * hs[4 * q] + w[q].y * hs[4 * q + 1]
           + w[q].z * hs[4 * q + 2] + w[q].w * hs[4 * q + 3];
    }
    gs[j] = acc;
    __syncthreads();
    if (j < LSTM2_H) {
      float ig = sigmoidf_(gs[j]);
      float fg = sigmoidf_(gs[LSTM2_H + j]);
      float gg = tanhf(gs[2 * LSTM2_H + j]);
      float og = sigmoidf_(gs[3 * LSTM2_H + j]);
      float c = fg * cs[j] + ig * gg;
      cs[j] = c;
      hs[j] = og * tanhf(c);
    }
    __syncthreads();
  }
  if (j < 4) {
    float acc = fcb[j];
    #pragma unroll
    for (int k = 0; k < LSTM2_H; ++k) acc += fcW[j * LSTM2_H + k] * hs[k];
    out[b * 4 + j] = acc;
  }
}

// ============================================================
extern "C" void kernel_launch(void* const* d_in, const int* in_sizes, int n_in,
                              void* d_out, int out_size, void* d_ws, size_t ws_size,
                              hipStream_t stream) {
  const float* x       = (const float*)d_in[0];
  const int*   eidx    = (const int*)d_in[1];
  const float* eattr   = (const float*)d_in[2];
  const float* g1_Wl   = (const float*)d_in[3];
  const float* g1_Wr   = (const float*)d_in[4];
  const float* g1_We   = (const float*)d_in[5];
  const float* g1_att  = (const float*)d_in[6];
  const float* g1_b    = (const float*)d_in[7];
  const float* g2_Wl   = (const float*)d_in[8];
  const float* g2_Wr   = (const float*)d_in[9];
  const float* g2_We   = (const float*)d_in[10];
  const float* g2_att  = (const float*)d_in[11];
  const float* g2_b    = (const float*)d_in[12];
  const float* l1_Wih  = (const float*)d_in[13];
  const float* l1_Whh  = (const float*)d_in[14];
  const float* l1_bih  = (const float*)d_in[15];
  const float* l1_bhh  = (const float*)d_in[16];
  const float* l2_Wih  = (const float*)d_in[17];
  const float* l2_Whh  = (const float*)d_in[18];
  const float* l2_bih  = (const float*)d_in[19];
  const float* l2_bhh  = (const float*)d_in[20];
  const float* fc_W    = (const float*)d_in[21];
  const float* fc_b    = (const float*)d_in[22];
  float* out = (float*)d_out;

  const int* src = eidx;
  const int* dst = eidx + E_EDGES;

  // workspace layout (fp32), chunked: peak ~96.3 MB
  float* ws = (float*)d_ws;
  float* h1c  = ws;                                   // CHUNK_N*512  (26 MB)
  float* xl2c = h1c + (size_t)CHUNK_N * HC;           // CHUNK_N*512  (26 MB)
  float* xr2c = xl2c + (size_t)CHUNK_N * HC;          // CHUNK_N*512  (26 MB)
  float* h2   = xr2c + (size_t)CHUNK_N * HC;          // N_TOTAL*64   (13 MB)
  float* X1   = h2 + (size_t)N_TOTAL * HID;           // G*512
  float* Y1   = X1 + (size_t)G_GRAPHS * 512;          // G*128
  float* X2   = Y1 + (size_t)G_GRAPHS * LSTM1_H;      // G*256
  float* ws_end = X2 + (size_t)G_GRAPHS * 256;

  // ws-size guard: if insufficient, launch nothing -> d_out stays zero ->
  // distinctive "absmax error == ref absmax (~2.7e-3)" signature instead of a
  // GPU memory fault. (Deterministic across calls: ws_size is fixed.)
  size_t needed = (size_t)(ws_end - ws) * sizeof(float);
  if (ws_size < needed) return;

  for (int c = 0; c < N_CHUNKS; ++c) {
    int g0 = c * CHUNK_G;
    // 1) GAT layer 1 -> h1c (CHUNK_N, 512), local rows
    gat1_kernel<<<CHUNK_G, 256, 0, stream>>>(x, src, dst, eattr, g1_Wl, g1_Wr, g1_We,
                                             g1_att, g1_b, h1c, g0);
    // 2) xl2c = h1c @ g2_Wl ; xr2c = h1c @ g2_Wr   (12672x512 @ 512x512)
    dim3 grid(HC / 64, CHUNK_N / 64);
    gemm_nn<<<grid, 256, 0, stream>>>(h1c, g2_Wl, xl2c, CHUNK_N, HC, HC);
    gemm_nn<<<grid, 256, 0, stream>>>(h1c, g2_Wr, xr2c, CHUNK_N, HC, HC);
    // 3) GAT layer 2 -> h2 (global rows)
    gat2_kernel<<<CHUNK_G, 256, 0, stream>>>(xl2c, xr2c, src, dst, eattr, g2_We,
                                             g2_att, g2_b, h2, g0);
  }

  // 4) LSTM1 input projection: X1 = seq @ l1_Wih^T + bih + bhh  (1536x2112 @ 512x2112^T)
  {
    dim3 grid(512 / 64, G_GRAPHS / 64);
    gemm_abt_bias<<<grid, 256, 0, stream>>>(h2, l1_Wih, l1_bih, l1_bhh, X1,
                                            G_GRAPHS, 512, N_NODES * HID);
  }

  // 5) LSTM1 recurrence -> Y1 (64,24,128)
  lstm1_kernel<<<BATCH, 512, 0, stream>>>(X1, l1_Whh, Y1);

  // 6) LSTM2 input projection: X2 = Y1 @ l2_Wih^T + biases
  x2_kernel<<<G_GRAPHS, 256, 0, stream>>>(Y1, l2_Wih, l2_bih, l2_bhh, X2);

  // 7) LSTM2 recurrence + FC -> out (64,4)
  lstm2_fc_kernel<<<BATCH, 256, 0, stream>>>(X2, l2_Whh, fc_W, fc_b, out);
}

// Round 3
// 980.758 us; speedup vs baseline: 2.1987x; 2.1987x over previous
//
#include <hip/hip_runtime.h>
#include <math.h>

// ---- problem constants ----
#define N_NODES 33
#define SEQ 24
#define BATCH 64
#define G_GRAPHS (BATCH * SEQ)          // 1536
#define EPG 64
#define E_EDGES (G_GRAPHS * EPG)        // 98304
#define N_TOTAL (G_GRAPHS * N_NODES)    // 50688
#define HID 64
#define HEADS 8
#define HC (HID * HEADS)                // 512
#define LSTM1_H 128
#define LSTM2_H 64
#define NEG_SLOPE 0.2f

// graph chunking: 6 chunks of 256 graphs keeps peak ws ~77 MB (<96.3 MB known-safe)
#define N_CHUNKS 6
#define CHUNK_G (G_GRAPHS / N_CHUNKS)   // 256 graphs
#define CHUNK_N (CHUNK_G * N_NODES)     // 8448 nodes (66 tiles of 128)

__device__ __forceinline__ float sigmoidf_(float x) { return 1.f / (1.f + expf(-x)); }
__device__ __forceinline__ float eluf_(float x) { return x > 0.f ? x : expm1f(x); }
__device__ __forceinline__ float lreluf_(float x) { return x > 0.f ? x : NEG_SLOPE * x; }

// bf16 (RNE) pack/unpack on raw shorts
__device__ __forceinline__ short f2bf(float x) {
  unsigned u = __float_as_uint(x);
  unsigned r = (u + 0x7fffu + ((u >> 16) & 1u)) >> 16;
  return (short)r;
}
__device__ __forceinline__ float bf2f(short b) {
  return __uint_as_float(((unsigned)(unsigned short)b) << 16);
}

typedef __attribute__((ext_vector_type(8))) short bf16x8;
typedef __attribute__((ext_vector_type(4))) float f32x4;

__device__ __forceinline__ void gl2lds16(const void* g, void* l) {
  __builtin_amdgcn_global_load_lds(
      (__attribute__((address_space(1))) const unsigned int*)g,
      (__attribute__((address_space(3))) unsigned int*)l, 16, 0, 0);
}

// ============================================================
// GAT layer 1 (unchanged math) -> h1 stored as bf16 hi/lo pair
// ============================================================
__global__ __launch_bounds__(256) void gat1_kernel(
    const float* __restrict__ x, const int* __restrict__ src, const int* __restrict__ dst,
    const float* __restrict__ ea, const float* __restrict__ Wl, const float* __restrict__ Wr,
    const float* __restrict__ We, const float* __restrict__ att, const float* __restrict__ bias,
    short* __restrict__ h1hi, short* __restrict__ h1lo, int g0) {
  __shared__ float Wl_s[2 * 512], Wr_s[2 * 512], We_s[3 * 512], att_s[512];
  __shared__ float xs[N_NODES][2], eas[EPG][3];
  __shared__ float logit[EPG][HEADS];
  __shared__ int sloc[EPG], dloc[EPG], deg[N_NODES], start[N_NODES], fill[N_NODES], elist[EPG];

  const int g = g0 + blockIdx.x, tid = threadIdx.x;
  const int nb = g * N_NODES, eb = g * EPG;
  const int lb = blockIdx.x * N_NODES;

  for (int i = tid; i < 1024; i += 256) { Wl_s[i] = Wl[i]; Wr_s[i] = Wr[i]; }
  for (int i = tid; i < 1536; i += 256) We_s[i] = We[i];
  for (int i = tid; i < 512; i += 256) att_s[i] = att[i];
  if (tid < 66) ((float*)xs)[tid] = x[nb * 2 + tid];
  for (int i = tid; i < EPG * 3; i += 256) ((float*)eas)[i] = ea[eb * 3 + i];
  if (tid < EPG) { sloc[tid] = src[eb + tid] - nb; dloc[tid] = dst[eb + tid] - nb; }
  if (tid < N_NODES) { deg[tid] = 0; fill[tid] = 0; }
  __syncthreads();
  if (tid < EPG) atomicAdd(&deg[dloc[tid]], 1);
  __syncthreads();
  if (tid == 0) { int a = 0; for (int n = 0; n < N_NODES; ++n) { start[n] = a; a += deg[n]; } }
  __syncthreads();
  if (tid < EPG) { int d = dloc[tid]; int p = atomicAdd(&fill[d], 1); elist[start[d] + p] = tid; }

  for (int t = tid; t < EPG * HEADS; t += 256) {
    int e = t >> 3, h = t & 7;
    int s = sloc[e], d = dloc[e];
    float xs0 = xs[s][0], xs1 = xs[s][1], xd0 = xs[d][0], xd1 = xs[d][1];
    float e0 = eas[e][0], e1 = eas[e][1], e2 = eas[e][2];
    float acc = 0.f;
    int base = h * 64;
    #pragma unroll 8
    for (int c = 0; c < 64; ++c) {
      int j = base + c;
      float v = xs0 * Wl_s[j] + xs1 * Wl_s[512 + j]
              + xd0 * Wr_s[j] + xd1 * Wr_s[512 + j]
              + e0 * We_s[j] + e1 * We_s[512 + j] + e2 * We_s[1024 + j];
      acc += lreluf_(v) * att_s[j];
    }
    logit[e][h] = acc;
  }
  __syncthreads();

  for (int t = tid; t < N_NODES * HEADS; t += 256) {
    int n = t >> 3, h = t & 7;
    int s0 = start[n], dn = deg[n];
    float mx = -1e30f;
    for (int i = 0; i < dn; ++i) mx = fmaxf(mx, logit[elist[s0 + i]][h]);
    float den = 0.f;
    for (int i = 0; i < dn; ++i) den += expf(logit[elist[s0 + i]][h] - mx);
    float inv = 1.f / (den + 1e-16f);
    for (int i = 0; i < dn; ++i) {
      int e = elist[s0 + i];
      logit[e][h] = expf(logit[e][h] - mx) * inv;
    }
  }
  __syncthreads();

  for (int t = tid; t < N_NODES * HC; t += 256) {
    int n = t >> 9, j = t & 511, h = j >> 6;
    int s0 = start[n], dn = deg[n];
    float acc = 0.f;
    for (int i = 0; i < dn; ++i) {
      int e = elist[s0 + i]; int s = sloc[e];
      float xlv = xs[s][0] * Wl_s[j] + xs[s][1] * Wl_s[512 + j];
      acc += logit[e][h] * xlv;
    }
    acc += bias[j];
    float v = eluf_(acc);
    short hi = f2bf(v);
    size_t o = (size_t)(lb + n) * HC + j;
    h1hi[o] = hi;
    h1lo[o] = f2bf(v - bf2f(hi));
  }
}

// ============================================================
// weight conversion: B2T[n][k] (n in [0,1024): Wl cols | Wr cols), hi/lo bf16
// ============================================================
__global__ __launch_bounds__(256) void conv_g2w(
    const float* __restrict__ Wl, const float* __restrict__ Wr,
    short* __restrict__ Bhi, short* __restrict__ Blo) {
  int idx = blockIdx.x * 256 + threadIdx.x;   // n*512 + k, 1024*512 total
  int n = idx >> 9, k = idx & 511;
  float v = (n < 512) ? Wl[k * 512 + n] : Wr[k * 512 + (n - 512)];
  short hi = f2bf(v);
  Bhi[idx] = hi;
  Blo[idx] = f2bf(v - bf2f(hi));
}

// l1_Wih is already [n][k]=(512,2112): elementwise hi/lo split
__global__ __launch_bounds__(256) void conv_w1(
    const float* __restrict__ W, short* __restrict__ Whi, short* __restrict__ Wlo, int total) {
  int idx = blockIdx.x * 256 + threadIdx.x;
  if (idx >= total) return;
  float v = W[idx];
  short hi = f2bf(v);
  Whi[idx] = hi;
  Wlo[idx] = f2bf(v - bf2f(hi));
}

// ============================================================
// split-bf16 MFMA GEMM: C[M,N] = (Ahi+Alo)[M,K] @ (Bhi+Blo)[N,K]^T (+biases)
// 3-term: AhBh + AhBl + AlBh. Tiles BM=32*WM? no: BM=32*WM, BN=32*WN with
// 4 waves in 2x2; wave tile = (WM*16)x(WN*16) of 16x16x32 MFMAs. BK=32.
// A and BT staged via global_load_lds width=16 into [row][k] 64B rows.
// ============================================================
template <int WM, int WN>
__global__ __launch_bounds__(256) void gemm_mfma(
    const short* __restrict__ Ahi, const short* __restrict__ Alo,
    const short* __restrict__ Bhi, const short* __restrict__ Blo,
    float* __restrict__ C, const float* __restrict__ bias1, const float* __restrict__ bias2,
    int M, int N, int K) {
  constexpr int BM = 32 * WM, BN = 32 * WN;
  __shared__ short lds[(BM + BN) * 32 * 2];
  short* Ah_s = lds;
  short* Bh_s = Ah_s + BM * 32;
  short* Al_s = Bh_s + BN * 32;
  short* Bl_s = Al_s + BM * 32;

  const int tid = threadIdx.x;
  const int wave = tid >> 6, lane = tid & 63;
  const int wm = wave >> 1, wn = wave & 1;
  const int bm = blockIdx.y * BM, bn = blockIdx.x * BN;

  const int rA = lane >> 2;          // 0..15 row within 16-row group
  const int cA = (lane & 3) * 8;     // bf16 col offset (8 bf16 = 16B)

  f32x4 acc[WM][WN];
  #pragma unroll
  for (int tm = 0; tm < WM; ++tm)
    #pragma unroll
    for (int tn = 0; tn < WN; ++tn) acc[tm][tn] = {0.f, 0.f, 0.f, 0.f};

  for (int k0 = 0; k0 < K; k0 += 32) {
    #pragma unroll
    for (int i = 0; i < BM / 64; ++i) {
      int row = i * 64 + wave * 16;                    // wave-uniform base row
      size_t go = (size_t)(bm + row + rA) * K + k0 + cA;
      int lo = (row)*32;                               // lds elem offset (uniform)
      gl2lds16(Ahi + go, Ah_s + lo);
      gl2lds16(Alo + go, Al_s + lo);
    }
    #pragma unroll
    for (int i = 0; i < BN / 64; ++i) {
      int row = i * 64 + wave * 16;
      size_t go = (size_t)(bn + row + rA) * K + k0 + cA;
      int lo = (row)*32;
      gl2lds16(Bhi + go, Bh_s + lo);
      gl2lds16(Blo + go, Bl_s + lo);
    }
    __syncthreads();

    bf16x8 a_h[WM], a_l[WM], b_h[WN], b_l[WN];
    const int fr = lane & 15;
    const int fk = (lane >> 4) * 8;
    #pragma unroll
    for (int tm = 0; tm < WM; ++tm) {
      int r = (wm * WM + tm) * 16 + fr;
      a_h[tm] = *(const bf16x8*)(Ah_s + r * 32 + fk);
      a_l[tm] = *(const bf16x8*)(Al_s + r * 32 + fk);
    }
    #pragma unroll
    for (int tn = 0; tn < WN; ++tn) {
      int r = (wn * WN + tn) * 16 + fr;
      b_h[tn] = *(const bf16x8*)(Bh_s + r * 32 + fk);
      b_l[tn] = *(const bf16x8*)(Bl_s + r * 32 + fk);
    }
    #pragma unroll
    for (int tm = 0; tm < WM; ++tm)
      #pragma unroll
      for (int tn = 0; tn < WN; ++tn) {
        acc[tm][tn] = __builtin_amdgcn_mfma_f32_16x16x32_bf16(a_h[tm], b_h[tn], acc[tm][tn], 0, 0, 0);
        acc[tm][tn] = __builtin_amdgcn_mfma_f32_16x16x32_bf16(a_h[tm], b_l[tn], acc[tm][tn], 0, 0, 0);
        acc[tm][tn] = __builtin_amdgcn_mfma_f32_16x16x32_bf16(a_l[tm], b_h[tn], acc[tm][tn], 0, 0, 0);
      }
    __syncthreads();
  }

  // epilogue: C/D layout col=lane&15, row=(lane>>4)*4+reg  [m89/m91 verified]
  const int col0 = lane & 15, rq = (lane >> 4) * 4;
  #pragma unroll
  for (int tm = 0; tm < WM; ++tm)
    #pragma unroll
    for (int tn = 0; tn < WN; ++tn) {
      int col = bn + (wn * WN + tn) * 16 + col0;
      float badd = 0.f;
      if (bias1) badd += bias1[col];
      if (bias2) badd += bias2[col];
      #pragma unroll
      for (int r = 0; r < 4; ++r) {
        int row = bm + (wm * WM + tm) * 16 + rq + r;
        C[(size_t)row * N + col] = acc[tm][tn][r] + badd;
      }
    }
}

// ============================================================
// GAT layer 2: reads combined xlr2c [row][1024] (xl | xr), writes h2 hi/lo bf16
// ============================================================
__global__ __launch_bounds__(256) void gat2_kernel(
    const float* __restrict__ xlr, const int* __restrict__ src, const int* __restrict__ dst,
    const float* __restrict__ ea, const float* __restrict__ We,
    const float* __restrict__ att, const float* __restrict__ bias,
    short* __restrict__ h2hi, short* __restrict__ h2lo, int g0) {
  __shared__ float We_s[3 * 512], att_s[512], b_s[HID];
  __shared__ float eas[EPG][3], logit[EPG][HEADS];
  __shared__ int sloc[EPG], dloc[EPG], deg[N_NODES], start[N_NODES], fill[N_NODES], elist[EPG];

  const int g = g0 + blockIdx.x, tid = threadIdx.x;
  const int nb = g * N_NODES, eb = g * EPG;
  const int lb = blockIdx.x * N_NODES;

  for (int i = tid; i < 1536; i += 256) We_s[i] = We[i];
  for (int i = tid; i < 512; i += 256) att_s[i] = att[i];
  if (tid < HID) b_s[tid] = bias[tid];
  for (int i = tid; i < EPG * 3; i += 256) ((float*)eas)[i] = ea[eb * 3 + i];
  if (tid < EPG) { sloc[tid] = src[eb + tid] - nb; dloc[tid] = dst[eb + tid] - nb; }
  if (tid < N_NODES) { deg[tid] = 0; fill[tid] = 0; }
  __syncthreads();
  if (tid < EPG) atomicAdd(&deg[dloc[tid]], 1);
  __syncthreads();
  if (tid == 0) { int a = 0; for (int n = 0; n < N_NODES; ++n) { start[n] = a; a += deg[n]; } }
  __syncthreads();
  if (tid < EPG) { int d = dloc[tid]; int p = atomicAdd(&fill[d], 1); elist[start[d] + p] = tid; }

  for (int t = tid; t < EPG * HEADS; t += 256) {
    int e = t >> 3, h = t & 7;
    const float* xl = xlr + (size_t)(lb + sloc[e]) * 1024 + h * 64;
    const float* xr = xlr + (size_t)(lb + dloc[e]) * 1024 + 512 + h * 64;
    float e0 = eas[e][0], e1 = eas[e][1], e2 = eas[e][2];
    float acc = 0.f;
    int base = h * 64;
    #pragma unroll 8
    for (int c = 0; c < 64; ++c) {
      int j = base + c;
      float v = xl[c] + xr[c] + e0 * We_s[j] + e1 * We_s[512 + j] + e2 * We_s[1024 + j];
      acc += lreluf_(v) * att_s[j];
    }
    logit[e][h] = acc;
  }
  __syncthreads();

  for (int t = tid; t < N_NODES * HEADS; t += 256) {
    int n = t >> 3, h = t & 7;
    int s0 = start[n], dn = deg[n];
    float mx = -1e30f;
    for (int i = 0; i < dn; ++i) mx = fmaxf(mx, logit[elist[s0 + i]][h]);
    float den = 0.f;
    for (int i = 0; i < dn; ++i) den += expf(logit[elist[s0 + i]][h] - mx);
    float inv = 1.f / (den + 1e-16f);
    for (int i = 0; i < dn; ++i) {
      int e = elist[s0 + i];
      logit[e][h] = expf(logit[e][h] - mx) * inv;
    }
  }
  __syncthreads();

  for (int t = tid; t < N_NODES * HID; t += 256) {
    int n = t >> 6, c = t & 63;
    int s0 = start[n], dn = deg[n];
    float acc = 0.f;
    for (int i = 0; i < dn; ++i) {
      int e = elist[s0 + i];
      const float* xl = xlr + (size_t)(lb + sloc[e]) * 1024 + c;
      #pragma unroll
      for (int h = 0; h < HEADS; ++h) acc += logit[e][h] * xl[h * 64];
    }
    acc = acc * 0.125f + b_s[c];
    float v = eluf_(acc);
    short hi = f2bf(v);
    size_t o = (size_t)(nb + n) * HID + c;   // == g*2112 + n*64 + c
    h2hi[o] = hi;
    h2lo[o] = f2bf(v - bf2f(hi));
  }
}

// ============================================================
// LSTM1 recurrence (unchanged)
// ============================================================
__global__ __launch_bounds__(512, 2) void lstm1_kernel(
    const float* __restrict__ X, const float* __restrict__ Whh, float* __restrict__ Y) {
  __shared__ float hs[LSTM1_H], cs[LSTM1_H], gs[4 * LSTM1_H];
  const int b = blockIdx.x, j = threadIdx.x;
  float4 w[32];
  const float4* wp = (const float4*)(Whh + (size_t)j * LSTM1_H);
  #pragma unroll
  for (int q = 0; q < 32; ++q) w[q] = wp[q];
  if (j < LSTM1_H) { hs[j] = 0.f; cs[j] = 0.f; }
  __syncthreads();
  for (int t = 0; t < SEQ; ++t) {
    float acc = X[((size_t)b * SEQ + t) * 512 + j];
    #pragma unroll
    for (int q = 0; q < 32; ++q) {
      acc += w[q].x * hs[4 * q] + w[q].y * hs[4 * q + 1]
           + w[q].z * hs[4 * q + 2] + w[q].w * hs[4 * q + 3];
    }
    gs[j] = acc;
    __syncthreads();
    if (j < LSTM1_H) {
      float ig = sigmoidf_(gs[j]);
      float fg = sigmoidf_(gs[LSTM1_H + j]);
      float gg = tanhf(gs[2 * LSTM1_H + j]);
      float og = sigmoidf_(gs[3 * LSTM1_H + j]);
      float c = fg * cs[j] + ig * gg;
      cs[j] = c;
      float h = og * tanhf(c);
      hs[j] = h;
      Y[((size_t)b * SEQ + t) * LSTM1_H + j] = h;
    }
    __syncthreads();
  }
}

__global__ __launch_bounds__(256) void x2_kernel(
    const float* __restrict__ Y1, const float* __restrict__ Wih,
    const float* __restrict__ bih, const float* __restrict__ bhh,
    float* __restrict__ X2) {
  __shared__ float ys[LSTM1_H];
  const int g = blockIdx.x, j = threadIdx.x;
  if (j < LSTM1_H) ys[j] = Y1[(size_t)g * LSTM1_H + j];
  __syncthreads();
  const float4* wp = (const float4*)(Wih + (size_t)j * LSTM1_H);
  float acc = bih[j] + bhh[j];
  #pragma unroll
  for (int q = 0; q < 32; ++q) {
    float4 w = wp[q];
    acc += w.x * ys[4 * q] + w.y * ys[4 * q + 1] + w.z * ys[4 * q + 2] + w.w * ys[4 * q + 3];
  }
  X2[(size_t)g * 256 + j] = acc;
}

__global__ __launch_bounds__(256, 2) void lstm2_fc_kernel(
    const float* __restrict__ X, const float* __restrict__ Whh,
    const float* __restrict__ fcW, const float* __restrict__ fcb,
    float* __restrict__ out) {
  __shared__ float hs[LSTM2_H], cs[LSTM2_H], gs[4 * LSTM2_H];
  const int b = blockIdx.x, j = threadIdx.x;
  float4 w[16];
  const float4* wp = (const float4*)(Whh + (size_t)j * LSTM2_H);
  #pragma unroll
  for (int q = 0; q < 16; ++q) w[q] = wp[q];
  if (j < LSTM2_H) { hs[j] = 0.f; cs[j] = 0.f; }
  __syncthreads();
  for (int t = 0; t < SEQ; ++t) {
    float acc = X[((size_t)b * SEQ + t) * 256 + j];
    #pragma unroll
    for (int q = 0; q < 16; ++q) {
      acc += w[q].x * hs[4 * q] + w[q].y * hs[4 * q + 1]
           + w[q].z * hs[4 * q + 2] + w[q].w * hs[4 * q + 3];
    }
    gs[j] = acc;
    __syncthreads();
    if (j < LSTM2_H) {
      float ig = sigmoidf_(gs[j]);
      float fg = sigmoidf_(gs[LSTM2_H + j]);
      float gg = tanhf(gs[2 * LSTM2_H + j]);
      float og = sigmoidf_(gs[3 * LSTM2_H + j]);
      float c = fg * cs[j] + ig * gg;
      cs[j] = c;
      hs[j] = og * tanhf(c);
    }
    __syncthreads();
  }
  if (j < 4) {
    float acc = fcb[j];
    #pragma unroll
    for (int k = 0; k < LSTM2_H; ++k) acc += fcW[j * LSTM2_H + k] * hs[k];
    out[b * 4 + j] = acc;
  }
}

// ============================================================
extern "C" void kernel_launch(void* const* d_in, const int* in_sizes, int n_in,
                              void* d_out, int out_size, void* d_ws, size_t ws_size,
                              hipStream_t stream) {
  const float* x       = (const float*)d_in[0];
  const int*   eidx    = (const int*)d_in[1];
  const float* eattr   = (const float*)d_in[2];
  const float* g1_Wl   = (const float*)d_in[3];
  const float* g1_Wr   = (const float*)d_in[4];
  const float* g1_We   = (const float*)d_in[5];
  const float* g1_att  = (const float*)d_in[6];
  const float* g1_b    = (const float*)d_in[7];
  const float* g2_Wl   = (const float*)d_in[8];
  const float* g2_Wr   = (const float*)d_in[9];
  const float* g2_We   = (const float*)d_in[10];
  const float* g2_att  = (const float*)d_in[11];
  const float* g2_b    = (const float*)d_in[12];
  const float* l1_Wih  = (const float*)d_in[13];
  const float* l1_Whh  = (const float*)d_in[14];
  const float* l1_bih  = (const float*)d_in[15];
  const float* l1_bhh  = (const float*)d_in[16];
  const float* l2_Wih  = (const float*)d_in[17];
  const float* l2_Whh  = (const float*)d_in[18];
  const float* l2_bih  = (const float*)d_in[19];
  const float* l2_bhh  = (const float*)d_in[20];
  const float* fc_W    = (const float*)d_in[21];
  const float* fc_b    = (const float*)d_in[22];
  float* out = (float*)d_out;

  const int* src = eidx;
  const int* dst = eidx + E_EDGES;

  // ---- workspace layout (256B-aligned chunks), peak ~77 MB ----
  char* p = (char*)d_ws;
  auto alloc = [&](size_t bytes) { char* r = p; p += (bytes + 255) & ~(size_t)255; return r; };
  short* h1hi  = (short*)alloc((size_t)CHUNK_N * HC * 2);        // 8.7 MB
  short* h1lo  = (short*)alloc((size_t)CHUNK_N * HC * 2);        // 8.7 MB
  float* xlr2c = (float*)alloc((size_t)CHUNK_N * 1024 * 4);      // 34.6 MB
  short* h2hi  = (short*)alloc((size_t)G_GRAPHS * 2112 * 2);     // 6.5 MB
  short* h2lo  = (short*)alloc((size_t)G_GRAPHS * 2112 * 2);     // 6.5 MB
  short* B2hi  = (short*)alloc((size_t)1024 * 512 * 2);          // 1.05 MB
  short* B2lo  = (short*)alloc((size_t)1024 * 512 * 2);
  short* W1hi  = (short*)alloc((size_t)512 * 2112 * 2);          // 2.2 MB
  short* W1lo  = (short*)alloc((size_t)512 * 2112 * 2);
  float* X1    = (float*)alloc((size_t)G_GRAPHS * 512 * 4);      // 3.1 MB
  float* Y1    = (float*)alloc((size_t)G_GRAPHS * LSTM1_H * 4);
  float* X2    = (float*)alloc((size_t)G_GRAPHS * 256 * 4);
  size_t needed = (size_t)(p - (char*)d_ws);
  if (ws_size < needed) return;   // guard: zero output instead of memory fault

  // 0) one-time weight conversions
  conv_g2w<<<(1024 * 512) / 256, 256, 0, stream>>>(g2_Wl, g2_Wr, B2hi, B2lo);
  conv_w1<<<(512 * 2112 + 255) / 256, 256, 0, stream>>>(l1_Wih, W1hi, W1lo, 512 * 2112);

  for (int c = 0; c < N_CHUNKS; ++c) {
    int g0 = c * CHUNK_G;
    gat1_kernel<<<CHUNK_G, 256, 0, stream>>>(x, src, dst, eattr, g1_Wl, g1_Wr, g1_We,
                                             g1_att, g1_b, h1hi, h1lo, g0);
    // [xl2|xr2] = h1 @ [Wl|Wr]  (8448x512 @ 512x1024) via split-bf16 MFMA
    dim3 grid(1024 / 128, CHUNK_N / 128);
    gemm_mfma<4, 4><<<grid, 256, 0, stream>>>(h1hi, h1lo, B2hi, B2lo, xlr2c,
                                              (const float*)nullptr, (const float*)nullptr,
                                              CHUNK_N, 1024, HC);
    gat2_kernel<<<CHUNK_G, 256, 0, stream>>>(xlr2c, src, dst, eattr, g2_We,
                                             g2_att, g2_b, h2hi, h2lo, g0);
  }

  // X1 = h2 @ l1_Wih^T + bih + bhh   (1536x2112 @ 512x2112^T)
  {
    dim3 grid(512 / 64, G_GRAPHS / 64);
    gemm_mfma<2, 2><<<grid, 256, 0, stream>>>(h2hi, h2lo, W1hi, W1lo, X1,
                                              l1_bih, l1_bhh,
                                              G_GRAPHS, 512, N_NODES * HID);
  }

  lstm1_kernel<<<BATCH, 512, 0, stream>>>(X1, l1_Whh, Y1);
  x2_kernel<<<G_GRAPHS, 256, 0, stream>>>(Y1, l2_Wih, l2_bih, l2_bhh, X2);
  lstm2_fc_kernel<<<BATCH, 256, 0, stream>>>(X2, l2_Whh, fc_W, fc_b, out);
}

// Round 4
// 838.039 us; speedup vs baseline: 2.5731x; 1.1703x over previous
//
#include <hip/hip_runtime.h>
#include <math.h>

// ---- problem constants ----
#define N_NODES 33
#define SEQ 24
#define BATCH 64
#define G_GRAPHS (BATCH * SEQ)          // 1536
#define EPG 64
#define E_EDGES (G_GRAPHS * EPG)        // 98304
#define N_TOTAL (G_GRAPHS * N_NODES)    // 50688
#define HID 64
#define HEADS 8
#define HC (HID * HEADS)                // 512
#define LSTM1_H 128
#define LSTM2_H 64
#define NEG_SLOPE 0.2f

// graph chunking: 6 chunks of 256 graphs keeps peak ws ~77 MB (<96.3 MB known-safe)
#define N_CHUNKS 6
#define CHUNK_G (G_GRAPHS / N_CHUNKS)   // 256 graphs
#define CHUNK_N (CHUNK_G * N_NODES)     // 8448 nodes (66 tiles of 128)

__device__ __forceinline__ float sigmoidf_(float x) { return 1.f / (1.f + expf(-x)); }
__device__ __forceinline__ float eluf_(float x) { return x > 0.f ? x : expm1f(x); }
__device__ __forceinline__ float lreluf_(float x) { return x > 0.f ? x : NEG_SLOPE * x; }

// bf16 (RNE) pack/unpack on raw shorts
__device__ __forceinline__ short f2bf(float x) {
  unsigned u = __float_as_uint(x);
  unsigned r = (u + 0x7fffu + ((u >> 16) & 1u)) >> 16;
  return (short)r;
}
__device__ __forceinline__ float bf2f(short b) {
  return __uint_as_float(((unsigned)(unsigned short)b) << 16);
}

typedef __attribute__((ext_vector_type(8))) short bf16x8;
typedef __attribute__((ext_vector_type(4))) float f32x4;

__device__ __forceinline__ void gl2lds16(const void* g, void* l) {
  __builtin_amdgcn_global_load_lds(
      (__attribute__((address_space(1))) const unsigned int*)g,
      (__attribute__((address_space(3))) unsigned int*)l, 16, 0, 0);
}

// ============================================================
// GAT layer 1 v2: conflict-free task maps, vectorized LDS reads & stores.
//  logits: h wave-uniform (weight reads broadcast), e = lane.
//  logit stored [8][65] padded (softmax/agg conflict-free).
//  aggregation: 8 channels/thread, short8 stores.
// ============================================================
__global__ __launch_bounds__(256) void gat1_kernel(
    const float* __restrict__ x, const int* __restrict__ src, const int* __restrict__ dst,
    const float* __restrict__ ea, const float* __restrict__ Wl, const float* __restrict__ Wr,
    const float* __restrict__ We, const float* __restrict__ att, const float* __restrict__ bias,
    short* __restrict__ h1hi, short* __restrict__ h1lo, int g0) {
  __shared__ alignas(16) float Wl_s[2 * 512];
  __shared__ alignas(16) float Wr_s[2 * 512];
  __shared__ alignas(16) float We_s[3 * 512];
  __shared__ alignas(16) float att_s[512];
  __shared__ float xs0_s[N_NODES + 1], xs1_s[N_NODES + 1];
  __shared__ float easX[EPG], easY[EPG], easZ[EPG];
  __shared__ float logit_s[HEADS * 65];   // padded stride 65
  __shared__ int sloc[EPG], dloc[EPG], deg[N_NODES], start[N_NODES], fill[N_NODES], elist[EPG];

  const int g = g0 + blockIdx.x, tid = threadIdx.x;
  const int nb = g * N_NODES, eb = g * EPG;
  const int lb = blockIdx.x * N_NODES;

  for (int i = tid; i < 1024; i += 256) { Wl_s[i] = Wl[i]; Wr_s[i] = Wr[i]; }
  for (int i = tid; i < 1536; i += 256) We_s[i] = We[i];
  for (int i = tid; i < 512; i += 256) att_s[i] = att[i];
  if (tid < 2 * N_NODES) {
    float v = x[nb * 2 + tid];
    if (tid & 1) xs1_s[tid >> 1] = v; else xs0_s[tid >> 1] = v;
  }
  if (tid < EPG) {
    easX[tid] = ea[(eb + tid) * 3 + 0];
    easY[tid] = ea[(eb + tid) * 3 + 1];
    easZ[tid] = ea[(eb + tid) * 3 + 2];
    sloc[tid] = src[eb + tid] - nb;
    dloc[tid] = dst[eb + tid] - nb;
  }
  if (tid < N_NODES) { deg[tid] = 0; fill[tid] = 0; }
  __syncthreads();
  if (tid < EPG) atomicAdd(&deg[dloc[tid]], 1);
  __syncthreads();
  if (tid == 0) { int a = 0; for (int n = 0; n < N_NODES; ++n) { start[n] = a; a += deg[n]; } }
  __syncthreads();
  if (tid < EPG) { int d = dloc[tid]; int p = atomicAdd(&fill[d], 1); elist[start[d] + p] = tid; }

  // logits: h = t>>6 (wave-uniform), e = t&63 (= lane). Weight reads broadcast.
  for (int t = tid; t < EPG * HEADS; t += 256) {
    int h = t >> 6, e = t & 63;
    int s = sloc[e], d = dloc[e];
    float xs0 = xs0_s[s], xs1 = xs1_s[s], xd0 = xs0_s[d], xd1 = xs1_s[d];
    float e0 = easX[e], e1 = easY[e], e2 = easZ[e];
    float acc = 0.f;
    int base = h * 64;
    #pragma unroll
    for (int c4 = 0; c4 < 16; ++c4) {
      int j = base + c4 * 4;
      f32x4 wl0 = *(const f32x4*)(Wl_s + j);
      f32x4 wl1 = *(const f32x4*)(Wl_s + 512 + j);
      f32x4 wr0 = *(const f32x4*)(Wr_s + j);
      f32x4 wr1 = *(const f32x4*)(Wr_s + 512 + j);
      f32x4 we0 = *(const f32x4*)(We_s + j);
      f32x4 we1 = *(const f32x4*)(We_s + 512 + j);
      f32x4 we2 = *(const f32x4*)(We_s + 1024 + j);
      f32x4 at  = *(const f32x4*)(att_s + j);
      #pragma unroll
      for (int q = 0; q < 4; ++q) {
        float v = xs0 * wl0[q] + xs1 * wl1[q]
                + xd0 * wr0[q] + xd1 * wr1[q]
                + e0 * we0[q] + e1 * we1[q] + e2 * we2[q];
        acc += lreluf_(v) * at[q];
      }
    }
    logit_s[h * 65 + e] = acc;
  }
  __syncthreads();

  // segment softmax: h = t>>6 (uniform), n = t&63 (lane), skip n>=33
  for (int t = tid; t < HEADS * 64; t += 256) {
    int h = t >> 6, n = t & 63;
    if (n < N_NODES) {
      int s0 = start[n], dn = deg[n];
      float mx = -1e30f;
      for (int i = 0; i < dn; ++i) mx = fmaxf(mx, logit_s[h * 65 + elist[s0 + i]]);
      float den = 0.f;
      for (int i = 0; i < dn; ++i) den += expf(logit_s[h * 65 + elist[s0 + i]] - mx);
      float inv = 1.f / (den + 1e-16f);
      for (int i = 0; i < dn; ++i) {
        int e = elist[s0 + i];
        logit_s[h * 65 + e] = expf(logit_s[h * 65 + e] - mx) * inv;
      }
    }
  }
  __syncthreads();

  // aggregation: task = (n, 8-channel block). n = t>>6 wave-uniform, jb = lane.
  for (int t = tid; t < N_NODES * 64; t += 256) {
    int n = t >> 6, jb = t & 63;
    int j0 = jb * 8, h = jb >> 3;
    f32x4 wa0 = *(const f32x4*)(Wl_s + j0);
    f32x4 wa1 = *(const f32x4*)(Wl_s + j0 + 4);
    f32x4 wb0 = *(const f32x4*)(Wl_s + 512 + j0);
    f32x4 wb1 = *(const f32x4*)(Wl_s + 512 + j0 + 4);
    float acc[8] = {};
    int s0 = start[n], dn = deg[n];
    for (int i = 0; i < dn; ++i) {
      int e = elist[s0 + i]; int s = sloc[e];
      float a = logit_s[h * 65 + e];
      float ax0 = a * xs0_s[s], ax1 = a * xs1_s[s];
      #pragma unroll
      for (int q = 0; q < 4; ++q) {
        acc[q]     += ax0 * wa0[q] + ax1 * wb0[q];
        acc[4 + q] += ax0 * wa1[q] + ax1 * wb1[q];
      }
    }
    f32x4 b0 = *(const f32x4*)(bias + j0);
    f32x4 b1 = *(const f32x4*)(bias + j0 + 4);
    bf16x8 vh, vl;
    #pragma unroll
    for (int cc = 0; cc < 8; ++cc) {
      float bb = (cc < 4) ? b0[cc] : b1[cc - 4];
      float v = eluf_(acc[cc] + bb);
      short hb = f2bf(v);
      vh[cc] = hb;
      vl[cc] = f2bf(v - bf2f(hb));
    }
    size_t o = (size_t)(lb + n) * HC + j0;
    *(bf16x8*)(h1hi + o) = vh;
    *(bf16x8*)(h1lo + o) = vl;
  }
}

// ============================================================
// weight conversion kernels (unchanged)
// ============================================================
__global__ __launch_bounds__(256) void conv_g2w(
    const float* __restrict__ Wl, const float* __restrict__ Wr,
    short* __restrict__ Bhi, short* __restrict__ Blo) {
  int idx = blockIdx.x * 256 + threadIdx.x;
  int n = idx >> 9, k = idx & 511;
  float v = (n < 512) ? Wl[k * 512 + n] : Wr[k * 512 + (n - 512)];
  short hi = f2bf(v);
  Bhi[idx] = hi;
  Blo[idx] = f2bf(v - bf2f(hi));
}

__global__ __launch_bounds__(256) void conv_w1(
    const float* __restrict__ W, short* __restrict__ Whi, short* __restrict__ Wlo, int total) {
  int idx = blockIdx.x * 256 + threadIdx.x;
  if (idx >= total) return;
  float v = W[idx];
  short hi = f2bf(v);
  Whi[idx] = hi;
  Wlo[idx] = f2bf(v - bf2f(hi));
}

// ============================================================
// split-bf16 MFMA GEMM (unchanged from round 3 — passed bit-exact)
// ============================================================
template <int WM, int WN>
__global__ __launch_bounds__(256) void gemm_mfma(
    const short* __restrict__ Ahi, const short* __restrict__ Alo,
    const short* __restrict__ Bhi, const short* __restrict__ Blo,
    float* __restrict__ C, const float* __restrict__ bias1, const float* __restrict__ bias2,
    int M, int N, int K) {
  constexpr int BM = 32 * WM, BN = 32 * WN;
  __shared__ short lds[(BM + BN) * 32 * 2];
  short* Ah_s = lds;
  short* Bh_s = Ah_s + BM * 32;
  short* Al_s = Bh_s + BN * 32;
  short* Bl_s = Al_s + BM * 32;

  const int tid = threadIdx.x;
  const int wave = tid >> 6, lane = tid & 63;
  const int wm = wave >> 1, wn = wave & 1;
  const int bm = blockIdx.y * BM, bn = blockIdx.x * BN;

  const int rA = lane >> 2;
  const int cA = (lane & 3) * 8;

  f32x4 acc[WM][WN];
  #pragma unroll
  for (int tm = 0; tm < WM; ++tm)
    #pragma unroll
    for (int tn = 0; tn < WN; ++tn) acc[tm][tn] = {0.f, 0.f, 0.f, 0.f};

  for (int k0 = 0; k0 < K; k0 += 32) {
    #pragma unroll
    for (int i = 0; i < BM / 64; ++i) {
      int row = i * 64 + wave * 16;
      size_t go = (size_t)(bm + row + rA) * K + k0 + cA;
      int lo = (row)*32;
      gl2lds16(Ahi + go, Ah_s + lo);
      gl2lds16(Alo + go, Al_s + lo);
    }
    #pragma unroll
    for (int i = 0; i < BN / 64; ++i) {
      int row = i * 64 + wave * 16;
      size_t go = (size_t)(bn + row + rA) * K + k0 + cA;
      int lo = (row)*32;
      gl2lds16(Bhi + go, Bh_s + lo);
      gl2lds16(Blo + go, Bl_s + lo);
    }
    __syncthreads();

    bf16x8 a_h[WM], a_l[WM], b_h[WN], b_l[WN];
    const int fr = lane & 15;
    const int fk = (lane >> 4) * 8;
    #pragma unroll
    for (int tm = 0; tm < WM; ++tm) {
      int r = (wm * WM + tm) * 16 + fr;
      a_h[tm] = *(const bf16x8*)(Ah_s + r * 32 + fk);
      a_l[tm] = *(const bf16x8*)(Al_s + r * 32 + fk);
    }
    #pragma unroll
    for (int tn = 0; tn < WN; ++tn) {
      int r = (wn * WN + tn) * 16 + fr;
      b_h[tn] = *(const bf16x8*)(Bh_s + r * 32 + fk);
      b_l[tn] = *(const bf16x8*)(Bl_s + r * 32 + fk);
    }
    #pragma unroll
    for (int tm = 0; tm < WM; ++tm)
      #pragma unroll
      for (int tn = 0; tn < WN; ++tn) {
        acc[tm][tn] = __builtin_amdgcn_mfma_f32_16x16x32_bf16(a_h[tm], b_h[tn], acc[tm][tn], 0, 0, 0);
        acc[tm][tn] = __builtin_amdgcn_mfma_f32_16x16x32_bf16(a_h[tm], b_l[tn], acc[tm][tn], 0, 0, 0);
        acc[tm][tn] = __builtin_amdgcn_mfma_f32_16x16x32_bf16(a_l[tm], b_h[tn], acc[tm][tn], 0, 0, 0);
      }
    __syncthreads();
  }

  const int col0 = lane & 15, rq = (lane >> 4) * 4;
  #pragma unroll
  for (int tm = 0; tm < WM; ++tm)
    #pragma unroll
    for (int tn = 0; tn < WN; ++tn) {
      int col = bn + (wn * WN + tn) * 16 + col0;
      float badd = 0.f;
      if (bias1) badd += bias1[col];
      if (bias2) badd += bias2[col];
      #pragma unroll
      for (int r = 0; r < 4; ++r) {
        int row = bm + (wm * WM + tm) * 16 + rq + r;
        C[(size_t)row * N + col] = acc[tm][tn][r] + badd;
      }
    }
}

// ============================================================
// GAT layer 2 v2: xl2/xr2 staged transposed [j][node] in LDS (conflict-free
// stride 33), wave-uniform weight broadcasts, short8 stores.
// ============================================================
__global__ __launch_bounds__(256) void gat2_kernel(
    const float* __restrict__ xlr, const int* __restrict__ src, const int* __restrict__ dst,
    const float* __restrict__ ea, const float* __restrict__ We,
    const float* __restrict__ att, const float* __restrict__ bias,
    short* __restrict__ h2hi, short* __restrict__ h2lo, int g0) {
  __shared__ float xl_s[512 * N_NODES];   // [j][s], 67.6 KB
  __shared__ float xr_s[512 * N_NODES];   // [j][d], 67.6 KB
  __shared__ alignas(16) float We_s[3 * 512];
  __shared__ alignas(16) float att_s[512];
  __shared__ float b_s[HID];
  __shared__ float easX[EPG], easY[EPG], easZ[EPG];
  __shared__ float logit_s[HEADS * 65];
  __shared__ int sloc[EPG], dloc[EPG], deg[N_NODES], start[N_NODES], fill[N_NODES], elist[EPG];

  const int g = g0 + blockIdx.x, tid = threadIdx.x;
  const int nb = g * N_NODES, eb = g * EPG;
  const int lb = blockIdx.x * N_NODES;

  for (int i = tid; i < 1536; i += 256) We_s[i] = We[i];
  for (int i = tid; i < 512; i += 256) att_s[i] = att[i];
  if (tid < HID) b_s[tid] = bias[tid];
  // stage xl/xr transposed: read coalesced, write bank=(j+s)%32 (conflict-free)
  for (int i = tid; i < N_NODES * 1024; i += 256) {
    int s = i >> 10, j = i & 1023;
    float v = xlr[(size_t)(lb + s) * 1024 + j];
    if (j < 512) xl_s[j * N_NODES + s] = v;
    else         xr_s[(j - 512) * N_NODES + s] = v;
  }
  if (tid < EPG) {
    easX[tid] = ea[(eb + tid) * 3 + 0];
    easY[tid] = ea[(eb + tid) * 3 + 1];
    easZ[tid] = ea[(eb + tid) * 3 + 2];
    sloc[tid] = src[eb + tid] - nb;
    dloc[tid] = dst[eb + tid] - nb;
  }
  if (tid < N_NODES) { deg[tid] = 0; fill[tid] = 0; }
  __syncthreads();
  if (tid < EPG) atomicAdd(&deg[dloc[tid]], 1);
  __syncthreads();
  if (tid == 0) { int a = 0; for (int n = 0; n < N_NODES; ++n) { start[n] = a; a += deg[n]; } }
  __syncthreads();
  if (tid < EPG) { int d = dloc[tid]; int p = atomicAdd(&fill[d], 1); elist[start[d] + p] = tid; }

  // logits: h wave-uniform, e = lane
  for (int t = tid; t < EPG * HEADS; t += 256) {
    int h = t >> 6, e = t & 63;
    int s = sloc[e], d = dloc[e];
    float e0 = easX[e], e1 = easY[e], e2 = easZ[e];
    float acc = 0.f;
    int base = h * 64;
    #pragma unroll
    for (int c4 = 0; c4 < 16; ++c4) {
      int j = base + c4 * 4;
      f32x4 we0 = *(const f32x4*)(We_s + j);
      f32x4 we1 = *(const f32x4*)(We_s + 512 + j);
      f32x4 we2 = *(const f32x4*)(We_s + 1024 + j);
      f32x4 at  = *(const f32x4*)(att_s + j);
      #pragma unroll
      for (int q = 0; q < 4; ++q) {
        int jj = j + q;
        float v = xl_s[jj * N_NODES + s] + xr_s[jj * N_NODES + d]
                + e0 * we0[q] + e1 * we1[q] + e2 * we2[q];
        acc += lreluf_(v) * at[q];
      }
    }
    logit_s[h * 65 + e] = acc;
  }
  __syncthreads();

  // softmax: h wave-uniform, n = lane (skip n>=33)
  for (int t = tid; t < HEADS * 64; t += 256) {
    int h = t >> 6, n = t & 63;
    if (n < N_NODES) {
      int s0 = start[n], dn = deg[n];
      float mx = -1e30f;
      for (int i = 0; i < dn; ++i) mx = fmaxf(mx, logit_s[h * 65 + elist[s0 + i]]);
      float den = 0.f;
      for (int i = 0; i < dn; ++i) den += expf(logit_s[h * 65 + elist[s0 + i]] - mx);
      float inv = 1.f / (den + 1e-16f);
      for (int i = 0; i < dn; ++i) {
        int e = elist[s0 + i];
        logit_s[h * 65 + e] = expf(logit_s[h * 65 + e] - mx) * inv;
      }
    }
  }
  __syncthreads();

  // aggregation: task = (n, 8-channel block of HID); head-mean fused (×0.125)
  for (int t = tid; t < N_NODES * 8; t += 256) {
    int n = t >> 3, jb = t & 7;
    int j0 = jb * 8;
    float acc[8] = {};
    int s0 = start[n], dn = deg[n];
    for (int i = 0; i < dn; ++i) {
      int e = elist[s0 + i]; int s = sloc[e];
      float al[8];
      #pragma unroll
      for (int h = 0; h < 8; ++h) al[h] = logit_s[h * 65 + e];
      #pragma unroll
      for (int cc = 0; cc < 8; ++cc) {
        int c = j0 + cc;
        float sum = 0.f;
        #pragma unroll
        for (int h = 0; h < 8; ++h) sum += al[h] * xl_s[(h * 64 + c) * N_NODES + s];
        acc[cc] += sum;
      }
    }
    bf16x8 vh, vl;
    #pragma unroll
    for (int cc = 0; cc < 8; ++cc) {
      float v = eluf_(acc[cc] * 0.125f + b_s[j0 + cc]);
      short hb = f2bf(v);
      vh[cc] = hb;
      vl[cc] = f2bf(v - bf2f(hb));
    }
    size_t o = (size_t)(nb + n) * HID + j0;
    *(bf16x8*)(h2hi + o) = vh;
    *(bf16x8*)(h2lo + o) = vl;
  }
}

// ============================================================
// LSTM chain (unchanged)
// ============================================================
__global__ __launch_bounds__(512, 2) void lstm1_kernel(
    const float* __restrict__ X, const float* __restrict__ Whh, float* __restrict__ Y) {
  __shared__ float hs[LSTM1_H], cs[LSTM1_H], gs[4 * LSTM1_H];
  const int b = blockIdx.x, j = threadIdx.x;
  float4 w[32];
  const float4* wp = (const float4*)(Whh + (size_t)j * LSTM1_H);
  #pragma unroll
  for (int q = 0; q < 32; ++q) w[q] = wp[q];
  if (j < LSTM1_H) { hs[j] = 0.f; cs[j] = 0.f; }
  __syncthreads();
  for (int t = 0; t < SEQ; ++t) {
    float acc = X[((size_t)b * SEQ + t) * 512 + j];
    #pragma unroll
    for (int q = 0; q < 32; ++q) {
      acc += w[q].x * hs[4 * q] + w[q].y * hs[4 * q + 1]
           + w[q].z * hs[4 * q + 2] + w[q].w * hs[4 * q + 3];
    }
    gs[j] = acc;
    __syncthreads();
    if (j < LSTM1_H) {
      float ig = sigmoidf_(gs[j]);
      float fg = sigmoidf_(gs[LSTM1_H + j]);
      float gg = tanhf(gs[2 * LSTM1_H + j]);
      float og = sigmoidf_(gs[3 * LSTM1_H + j]);
      float c = fg * cs[j] + ig * gg;
      cs[j] = c;
      float h = og * tanhf(c);
      hs[j] = h;
      Y[((size_t)b * SEQ + t) * LSTM1_H + j] = h;
    }
    __syncthreads();
  }
}

__global__ __launch_bounds__(256) void x2_kernel(
    const float* __restrict__ Y1, const float* __restrict__ Wih,
    const float* __restrict__ bih, const float* __restrict__ bhh,
    float* __restrict__ X2) {
  __shared__ float ys[LSTM1_H];
  const int g = blockIdx.x, j = threadIdx.x;
  if (j < LSTM1_H) ys[j] = Y1[(size_t)g * LSTM1_H + j];
  __syncthreads();
  const float4* wp = (const float4*)(Wih + (size_t)j * LSTM1_H);
  float acc = bih[j] + bhh[j];
  #pragma unroll
  for (int q = 0; q < 32; ++q) {
    float4 w = wp[q];
    acc += w.x * ys[4 * q] + w.y * ys[4 * q + 1] + w.z * ys[4 * q + 2] + w.w * ys[4 * q + 3];
  }
  X2[(size_t)g * 256 + j] = acc;
}

__global__ __launch_bounds__(256, 2) void lstm2_fc_kernel(
    const float* __restrict__ X, const float* __restrict__ Whh,
    const float* __restrict__ fcW, const float* __restrict__ fcb,
    float* __restrict__ out) {
  __shared__ float hs[LSTM2_H], cs[LSTM2_H], gs[4 * LSTM2_H];
  const int b = blockIdx.x, j = threadIdx.x;
  float4 w[16];
  const float4* wp = (const float4*)(Whh + (size_t)j * LSTM2_H);
  #pragma unroll
  for (int q = 0; q < 16; ++q) w[q] = wp[q];
  if (j < LSTM2_H) { hs[j] = 0.f; cs[j] = 0.f; }
  __syncthreads();
  for (int t = 0; t < SEQ; ++t) {
    float acc = X[((size_t)b * SEQ + t) * 256 + j];
    #pragma unroll
    for (int q = 0; q < 16; ++q) {
      acc += w[q].x * hs[4 * q] + w[q].y * hs[4 * q + 1]
           + w[q].z * hs[4 * q + 2] + w[q].w * hs[4 * q + 3];
    }
    gs[j] = acc;
    __syncthreads();
    if (j < LSTM2_H) {
      float ig = sigmoidf_(gs[j]);
      float fg = sigmoidf_(gs[LSTM2_H + j]);
      float gg = tanhf(gs[2 * LSTM2_H + j]);
      float og = sigmoidf_(gs[3 * LSTM2_H + j]);
      float c = fg * cs[j] + ig * gg;
      cs[j] = c;
      hs[j] = og * tanhf(c);
    }
    __syncthreads();
  }
  if (j < 4) {
    float acc = fcb[j];
    #pragma unroll
    for (int k = 0; k < LSTM2_H; ++k) acc += fcW[j * LSTM2_H + k] * hs[k];
    out[b * 4 + j] = acc;
  }
}

// ============================================================
extern "C" void kernel_launch(void* const* d_in, const int* in_sizes, int n_in,
                              void* d_out, int out_size, void* d_ws, size_t ws_size,
                              hipStream_t stream) {
  const float* x       = (const float*)d_in[0];
  const int*   eidx    = (const int*)d_in[1];
  const float* eattr   = (const float*)d_in[2];
  const float* g1_Wl   = (const float*)d_in[3];
  const float* g1_Wr   = (const float*)d_in[4];
  const float* g1_We   = (const float*)d_in[5];
  const float* g1_att  = (const float*)d_in[6];
  const float* g1_b    = (const float*)d_in[7];
  const float* g2_Wl   = (const float*)d_in[8];
  const float* g2_Wr   = (const float*)d_in[9];
  const float* g2_We   = (const float*)d_in[10];
  const float* g2_att  = (const float*)d_in[11];
  const float* g2_b    = (const float*)d_in[12];
  const float* l1_Wih  = (const float*)d_in[13];
  const float* l1_Whh  = (const float*)d_in[14];
  const float* l1_bih  = (const float*)d_in[15];
  const float* l1_bhh  = (const float*)d_in[16];
  const float* l2_Wih  = (const float*)d_in[17];
  const float* l2_Whh  = (const float*)d_in[18];
  const float* l2_bih  = (const float*)d_in[19];
  const float* l2_bhh  = (const float*)d_in[20];
  const float* fc_W    = (const float*)d_in[21];
  const float* fc_b    = (const float*)d_in[22];
  float* out = (float*)d_out;

  const int* src = eidx;
  const int* dst = eidx + E_EDGES;

  // ---- workspace layout (256B-aligned chunks), peak ~77 MB ----
  char* p = (char*)d_ws;
  auto alloc = [&](size_t bytes) { char* r = p; p += (bytes + 255) & ~(size_t)255; return r; };
  short* h1hi  = (short*)alloc((size_t)CHUNK_N * HC * 2);
  short* h1lo  = (short*)alloc((size_t)CHUNK_N * HC * 2);
  float* xlr2c = (float*)alloc((size_t)CHUNK_N * 1024 * 4);
  short* h2hi  = (short*)alloc((size_t)G_GRAPHS * 2112 * 2);
  short* h2lo  = (short*)alloc((size_t)G_GRAPHS * 2112 * 2);
  short* B2hi  = (short*)alloc((size_t)1024 * 512 * 2);
  short* B2lo  = (short*)alloc((size_t)1024 * 512 * 2);
  short* W1hi  = (short*)alloc((size_t)512 * 2112 * 2);
  short* W1lo  = (short*)alloc((size_t)512 * 2112 * 2);
  float* X1    = (float*)alloc((size_t)G_GRAPHS * 512 * 4);
  float* Y1    = (float*)alloc((size_t)G_GRAPHS * LSTM1_H * 4);
  float* X2    = (float*)alloc((size_t)G_GRAPHS * 256 * 4);
  size_t needed = (size_t)(p - (char*)d_ws);
  if (ws_size < needed) return;   // guard: zero output instead of memory fault

  conv_g2w<<<(1024 * 512) / 256, 256, 0, stream>>>(g2_Wl, g2_Wr, B2hi, B2lo);
  conv_w1<<<(512 * 2112 + 255) / 256, 256, 0, stream>>>(l1_Wih, W1hi, W1lo, 512 * 2112);

  for (int c = 0; c < N_CHUNKS; ++c) {
    int g0 = c * CHUNK_G;
    gat1_kernel<<<CHUNK_G, 256, 0, stream>>>(x, src, dst, eattr, g1_Wl, g1_Wr, g1_We,
                                             g1_att, g1_b, h1hi, h1lo, g0);
    dim3 grid(1024 / 128, CHUNK_N / 128);
    gemm_mfma<4, 4><<<grid, 256, 0, stream>>>(h1hi, h1lo, B2hi, B2lo, xlr2c,
                                              (const float*)nullptr, (const float*)nullptr,
                                              CHUNK_N, 1024, HC);
    gat2_kernel<<<CHUNK_G, 256, 0, stream>>>(xlr2c, src, dst, eattr, g2_We,
                                             g2_att, g2_b, h2hi, h2lo, g0);
  }

  {
    dim3 grid(512 / 64, G_GRAPHS / 64);
    gemm_mfma<2, 2><<<grid, 256, 0, stream>>>(h2hi, h2lo, W1hi, W1lo, X1,
                                              l1_bih, l1_bhh,
                                              G_GRAPHS, 512, N_NODES * HID);
  }

  lstm1_kernel<<<BATCH, 512, 0, stream>>>(X1, l1_Whh, Y1);
  x2_kernel<<<G_GRAPHS, 256, 0, stream>>>(Y1, l2_Wih, l2_bih, l2_bhh, X2);
  lstm2_fc_kernel<<<BATCH, 256, 0, stream>>>(X2, l2_Whh, fc_W, fc_b, out);
}

// Round 5
// 834.666 us; speedup vs baseline: 2.5835x; 1.0040x over previous
//
#include <hip/hip_runtime.h>
#include <math.h>

// ---- problem constants ----
#define N_NODES 33
#define SEQ 24
#define BATCH 64
#define G_GRAPHS (BATCH * SEQ)          // 1536
#define EPG 64
#define E_EDGES (G_GRAPHS * EPG)        // 98304
#define N_TOTAL (G_GRAPHS * N_NODES)    // 50688
#define HID 64
#define HEADS 8
#define HC (HID * HEADS)                // 512
#define LSTM1_H 128
#define LSTM2_H 64
#define NEG_SLOPE 0.2f

// graph chunking: 6 chunks of 256 graphs keeps peak ws ~77 MB (<96.3 MB known-safe)
#define N_CHUNKS 6
#define CHUNK_G (G_GRAPHS / N_CHUNKS)   // 256 graphs
#define CHUNK_N (CHUNK_G * N_NODES)     // 8448 nodes

__device__ __forceinline__ float sigmoidf_(float x) { return 1.f / (1.f + expf(-x)); }
__device__ __forceinline__ float eluf_(float x) { return x > 0.f ? x : expm1f(x); }
__device__ __forceinline__ float lreluf_(float x) { return x > 0.f ? x : NEG_SLOPE * x; }

// bf16 (RNE) pack/unpack on raw shorts
__device__ __forceinline__ short f2bf(float x) {
  unsigned u = __float_as_uint(x);
  unsigned r = (u + 0x7fffu + ((u >> 16) & 1u)) >> 16;
  return (short)r;
}
__device__ __forceinline__ float bf2f(short b) {
  return __uint_as_float(((unsigned)(unsigned short)b) << 16);
}

typedef __attribute__((ext_vector_type(8))) short bf16x8;
typedef __attribute__((ext_vector_type(4))) float f32x4;

__device__ __forceinline__ void gl2lds16(const void* g, void* l) {
  __builtin_amdgcn_global_load_lds(
      (__attribute__((address_space(1))) const unsigned int*)g,
      (__attribute__((address_space(3))) unsigned int*)l, 16, 0, 0);
}

// ============================================================
// GAT layer 1 (round-4 version — conflict-free, verified)
// ============================================================
__global__ __launch_bounds__(256) void gat1_kernel(
    const float* __restrict__ x, const int* __restrict__ src, const int* __restrict__ dst,
    const float* __restrict__ ea, const float* __restrict__ Wl, const float* __restrict__ Wr,
    const float* __restrict__ We, const float* __restrict__ att, const float* __restrict__ bias,
    short* __restrict__ h1hi, short* __restrict__ h1lo, int g0) {
  __shared__ alignas(16) float Wl_s[2 * 512];
  __shared__ alignas(16) float Wr_s[2 * 512];
  __shared__ alignas(16) float We_s[3 * 512];
  __shared__ alignas(16) float att_s[512];
  __shared__ float xs0_s[N_NODES + 1], xs1_s[N_NODES + 1];
  __shared__ float easX[EPG], easY[EPG], easZ[EPG];
  __shared__ float logit_s[HEADS * 65];   // padded stride 65
  __shared__ int sloc[EPG], dloc[EPG], deg[N_NODES], start[N_NODES], fill[N_NODES], elist[EPG];

  const int g = g0 + blockIdx.x, tid = threadIdx.x;
  const int nb = g * N_NODES, eb = g * EPG;
  const int lb = blockIdx.x * N_NODES;

  for (int i = tid; i < 1024; i += 256) { Wl_s[i] = Wl[i]; Wr_s[i] = Wr[i]; }
  for (int i = tid; i < 1536; i += 256) We_s[i] = We[i];
  for (int i = tid; i < 512; i += 256) att_s[i] = att[i];
  if (tid < 2 * N_NODES) {
    float v = x[nb * 2 + tid];
    if (tid & 1) xs1_s[tid >> 1] = v; else xs0_s[tid >> 1] = v;
  }
  if (tid < EPG) {
    easX[tid] = ea[(eb + tid) * 3 + 0];
    easY[tid] = ea[(eb + tid) * 3 + 1];
    easZ[tid] = ea[(eb + tid) * 3 + 2];
    sloc[tid] = src[eb + tid] - nb;
    dloc[tid] = dst[eb + tid] - nb;
  }
  if (tid < N_NODES) { deg[tid] = 0; fill[tid] = 0; }
  __syncthreads();
  if (tid < EPG) atomicAdd(&deg[dloc[tid]], 1);
  __syncthreads();
  if (tid == 0) { int a = 0; for (int n = 0; n < N_NODES; ++n) { start[n] = a; a += deg[n]; } }
  __syncthreads();
  if (tid < EPG) { int d = dloc[tid]; int p = atomicAdd(&fill[d], 1); elist[start[d] + p] = tid; }

  // logits: h = t>>6 (wave-uniform), e = t&63 (= lane). Weight reads broadcast.
  for (int t = tid; t < EPG * HEADS; t += 256) {
    int h = t >> 6, e = t & 63;
    int s = sloc[e], d = dloc[e];
    float xs0 = xs0_s[s], xs1 = xs1_s[s], xd0 = xs0_s[d], xd1 = xs1_s[d];
    float e0 = easX[e], e1 = easY[e], e2 = easZ[e];
    float acc = 0.f;
    int base = h * 64;
    #pragma unroll
    for (int c4 = 0; c4 < 16; ++c4) {
      int j = base + c4 * 4;
      f32x4 wl0 = *(const f32x4*)(Wl_s + j);
      f32x4 wl1 = *(const f32x4*)(Wl_s + 512 + j);
      f32x4 wr0 = *(const f32x4*)(Wr_s + j);
      f32x4 wr1 = *(const f32x4*)(Wr_s + 512 + j);
      f32x4 we0 = *(const f32x4*)(We_s + j);
      f32x4 we1 = *(const f32x4*)(We_s + 512 + j);
      f32x4 we2 = *(const f32x4*)(We_s + 1024 + j);
      f32x4 at  = *(const f32x4*)(att_s + j);
      #pragma unroll
      for (int q = 0; q < 4; ++q) {
        float v = xs0 * wl0[q] + xs1 * wl1[q]
                + xd0 * wr0[q] + xd1 * wr1[q]
                + e0 * we0[q] + e1 * we1[q] + e2 * we2[q];
        acc += lreluf_(v) * at[q];
      }
    }
    logit_s[h * 65 + e] = acc;
  }
  __syncthreads();

  // segment softmax: h = t>>6 (uniform), n = t&63 (lane), skip n>=33
  for (int t = tid; t < HEADS * 64; t += 256) {
    int h = t >> 6, n = t & 63;
    if (n < N_NODES) {
      int s0 = start[n], dn = deg[n];
      float mx = -1e30f;
      for (int i = 0; i < dn; ++i) mx = fmaxf(mx, logit_s[h * 65 + elist[s0 + i]]);
      float den = 0.f;
      for (int i = 0; i < dn; ++i) den += expf(logit_s[h * 65 + elist[s0 + i]] - mx);
      float inv = 1.f / (den + 1e-16f);
      for (int i = 0; i < dn; ++i) {
        int e = elist[s0 + i];
        logit_s[h * 65 + e] = expf(logit_s[h * 65 + e] - mx) * inv;
      }
    }
  }
  __syncthreads();

  // aggregation: task = (n, 8-channel block). n = t>>6 wave-uniform, jb = lane.
  for (int t = tid; t < N_NODES * 64; t += 256) {
    int n = t >> 6, jb = t & 63;
    int j0 = jb * 8, h = jb >> 3;
    f32x4 wa0 = *(const f32x4*)(Wl_s + j0);
    f32x4 wa1 = *(const f32x4*)(Wl_s + j0 + 4);
    f32x4 wb0 = *(const f32x4*)(Wl_s + 512 + j0);
    f32x4 wb1 = *(const f32x4*)(Wl_s + 512 + j0 + 4);
    float acc[8] = {};
    int s0 = start[n], dn = deg[n];
    for (int i = 0; i < dn; ++i) {
      int e = elist[s0 + i]; int s = sloc[e];
      float a = logit_s[h * 65 + e];
      float ax0 = a * xs0_s[s], ax1 = a * xs1_s[s];
      #pragma unroll
      for (int q = 0; q < 4; ++q) {
        acc[q]     += ax0 * wa0[q] + ax1 * wb0[q];
        acc[4 + q] += ax0 * wa1[q] + ax1 * wb1[q];
      }
    }
    f32x4 b0 = *(const f32x4*)(bias + j0);
    f32x4 b1 = *(const f32x4*)(bias + j0 + 4);
    bf16x8 vh, vl;
    #pragma unroll
    for (int cc = 0; cc < 8; ++cc) {
      float bb = (cc < 4) ? b0[cc] : b1[cc - 4];
      float v = eluf_(acc[cc] + bb);
      short hb = f2bf(v);
      vh[cc] = hb;
      vl[cc] = f2bf(v - bf2f(hb));
    }
    size_t o = (size_t)(lb + n) * HC + j0;
    *(bf16x8*)(h1hi + o) = vh;
    *(bf16x8*)(h1lo + o) = vl;
  }
}

// ============================================================
// weight conversion kernels (unchanged)
// ============================================================
__global__ __launch_bounds__(256) void conv_g2w(
    const float* __restrict__ Wl, const float* __restrict__ Wr,
    short* __restrict__ Bhi, short* __restrict__ Blo) {
  int idx = blockIdx.x * 256 + threadIdx.x;
  int n = idx >> 9, k = idx & 511;
  float v = (n < 512) ? Wl[k * 512 + n] : Wr[k * 512 + (n - 512)];
  short hi = f2bf(v);
  Bhi[idx] = hi;
  Blo[idx] = f2bf(v - bf2f(hi));
}

__global__ __launch_bounds__(256) void conv_w1(
    const float* __restrict__ W, short* __restrict__ Whi, short* __restrict__ Wlo, int total) {
  int idx = blockIdx.x * 256 + threadIdx.x;
  if (idx >= total) return;
  float v = W[idx];
  short hi = f2bf(v);
  Whi[idx] = hi;
  Wlo[idx] = f2bf(v - bf2f(hi));
}

// ============================================================
// split-bf16 MFMA GEMM (unchanged math — passed bit-exact)
// ============================================================
template <int WM, int WN>
__global__ __launch_bounds__(256) void gemm_mfma(
    const short* __restrict__ Ahi, const short* __restrict__ Alo,
    const short* __restrict__ Bhi, const short* __restrict__ Blo,
    float* __restrict__ C, const float* __restrict__ bias1, const float* __restrict__ bias2,
    int M, int N, int K) {
  constexpr int BM = 32 * WM, BN = 32 * WN;
  __shared__ short lds[(BM + BN) * 32 * 2];
  short* Ah_s = lds;
  short* Bh_s = Ah_s + BM * 32;
  short* Al_s = Bh_s + BN * 32;
  short* Bl_s = Al_s + BM * 32;

  const int tid = threadIdx.x;
  const int wave = tid >> 6, lane = tid & 63;
  const int wm = wave >> 1, wn = wave & 1;
  const int bm = blockIdx.y * BM, bn = blockIdx.x * BN;

  const int rA = lane >> 2;
  const int cA = (lane & 3) * 8;

  f32x4 acc[WM][WN];
  #pragma unroll
  for (int tm = 0; tm < WM; ++tm)
    #pragma unroll
    for (int tn = 0; tn < WN; ++tn) acc[tm][tn] = {0.f, 0.f, 0.f, 0.f};

  for (int k0 = 0; k0 < K; k0 += 32) {
    #pragma unroll
    for (int i = 0; i < BM / 64; ++i) {
      int row = i * 64 + wave * 16;
      size_t go = (size_t)(bm + row + rA) * K + k0 + cA;
      int lo = (row)*32;
      gl2lds16(Ahi + go, Ah_s + lo);
      gl2lds16(Alo + go, Al_s + lo);
    }
    #pragma unroll
    for (int i = 0; i < BN / 64; ++i) {
      int row = i * 64 + wave * 16;
      size_t go = (size_t)(bn + row + rA) * K + k0 + cA;
      int lo = (row)*32;
      gl2lds16(Bhi + go, Bh_s + lo);
      gl2lds16(Blo + go, Bl_s + lo);
    }
    __syncthreads();

    bf16x8 a_h[WM], a_l[WM], b_h[WN], b_l[WN];
    const int fr = lane & 15;
    const int fk = (lane >> 4) * 8;
    #pragma unroll
    for (int tm = 0; tm < WM; ++tm) {
      int r = (wm * WM + tm) * 16 + fr;
      a_h[tm] = *(const bf16x8*)(Ah_s + r * 32 + fk);
      a_l[tm] = *(const bf16x8*)(Al_s + r * 32 + fk);
    }
    #pragma unroll
    for (int tn = 0; tn < WN; ++tn) {
      int r = (wn * WN + tn) * 16 + fr;
      b_h[tn] = *(const bf16x8*)(Bh_s + r * 32 + fk);
      b_l[tn] = *(const bf16x8*)(Bl_s + r * 32 + fk);
    }
    #pragma unroll
    for (int tm = 0; tm < WM; ++tm)
      #pragma unroll
      for (int tn = 0; tn < WN; ++tn) {
        acc[tm][tn] = __builtin_amdgcn_mfma_f32_16x16x32_bf16(a_h[tm], b_h[tn], acc[tm][tn], 0, 0, 0);
        acc[tm][tn] = __builtin_amdgcn_mfma_f32_16x16x32_bf16(a_h[tm], b_l[tn], acc[tm][tn], 0, 0, 0);
        acc[tm][tn] = __builtin_amdgcn_mfma_f32_16x16x32_bf16(a_l[tm], b_h[tn], acc[tm][tn], 0, 0, 0);
      }
    __syncthreads();
  }

  const int col0 = lane & 15, rq = (lane >> 4) * 4;
  #pragma unroll
  for (int tm = 0; tm < WM; ++tm)
    #pragma unroll
    for (int tn = 0; tn < WN; ++tn) {
      int col = bn + (wn * WN + tn) * 16 + col0;
      float badd = 0.f;
      if (bias1) badd += bias1[col];
      if (bias2) badd += bias2[col];
      #pragma unroll
      for (int r = 0; r < 4; ++r) {
        int row = bm + (wm * WM + tm) * 16 + rq + r;
        C[(size_t)row * N + col] = acc[tm][tn][r] + badd;
      }
    }
}

// ============================================================
// GAT layer 2 (round-4 version — verified)
// ============================================================
__global__ __launch_bounds__(256) void gat2_kernel(
    const float* __restrict__ xlr, const int* __restrict__ src, const int* __restrict__ dst,
    const float* __restrict__ ea, const float* __restrict__ We,
    const float* __restrict__ att, const float* __restrict__ bias,
    short* __restrict__ h2hi, short* __restrict__ h2lo, int g0) {
  __shared__ float xl_s[512 * N_NODES];   // [j][s]
  __shared__ float xr_s[512 * N_NODES];   // [j][d]
  __shared__ alignas(16) float We_s[3 * 512];
  __shared__ alignas(16) float att_s[512];
  __shared__ float b_s[HID];
  __shared__ float easX[EPG], easY[EPG], easZ[EPG];
  __shared__ float logit_s[HEADS * 65];
  __shared__ int sloc[EPG], dloc[EPG], deg[N_NODES], start[N_NODES], fill[N_NODES], elist[EPG];

  const int g = g0 + blockIdx.x, tid = threadIdx.x;
  const int nb = g * N_NODES, eb = g * EPG;
  const int lb = blockIdx.x * N_NODES;

  for (int i = tid; i < 1536; i += 256) We_s[i] = We[i];
  for (int i = tid; i < 512; i += 256) att_s[i] = att[i];
  if (tid < HID) b_s[tid] = bias[tid];
  for (int i = tid; i < N_NODES * 1024; i += 256) {
    int s = i >> 10, j = i & 1023;
    float v = xlr[(size_t)(lb + s) * 1024 + j];
    if (j < 512) xl_s[j * N_NODES + s] = v;
    else         xr_s[(j - 512) * N_NODES + s] = v;
  }
  if (tid < EPG) {
    easX[tid] = ea[(eb + tid) * 3 + 0];
    easY[tid] = ea[(eb + tid) * 3 + 1];
    easZ[tid] = ea[(eb + tid) * 3 + 2];
    sloc[tid] = src[eb + tid] - nb;
    dloc[tid] = dst[eb + tid] - nb;
  }
  if (tid < N_NODES) { deg[tid] = 0; fill[tid] = 0; }
  __syncthreads();
  if (tid < EPG) atomicAdd(&deg[dloc[tid]], 1);
  __syncthreads();
  if (tid == 0) { int a = 0; for (int n = 0; n < N_NODES; ++n) { start[n] = a; a += deg[n]; } }
  __syncthreads();
  if (tid < EPG) { int d = dloc[tid]; int p = atomicAdd(&fill[d], 1); elist[start[d] + p] = tid; }

  for (int t = tid; t < EPG * HEADS; t += 256) {
    int h = t >> 6, e = t & 63;
    int s = sloc[e], d = dloc[e];
    float e0 = easX[e], e1 = easY[e], e2 = easZ[e];
    float acc = 0.f;
    int base = h * 64;
    #pragma unroll
    for (int c4 = 0; c4 < 16; ++c4) {
      int j = base + c4 * 4;
      f32x4 we0 = *(const f32x4*)(We_s + j);
      f32x4 we1 = *(const f32x4*)(We_s + 512 + j);
      f32x4 we2 = *(const f32x4*)(We_s + 1024 + j);
      f32x4 at  = *(const f32x4*)(att_s + j);
      #pragma unroll
      for (int q = 0; q < 4; ++q) {
        int jj = j + q;
        float v = xl_s[jj * N_NODES + s] + xr_s[jj * N_NODES + d]
                + e0 * we0[q] + e1 * we1[q] + e2 * we2[q];
        acc += lreluf_(v) * at[q];
      }
    }
    logit_s[h * 65 + e] = acc;
  }
  __syncthreads();

  for (int t = tid; t < HEADS * 64; t += 256) {
    int h = t >> 6, n = t & 63;
    if (n < N_NODES) {
      int s0 = start[n], dn = deg[n];
      float mx = -1e30f;
      for (int i = 0; i < dn; ++i) mx = fmaxf(mx, logit_s[h * 65 + elist[s0 + i]]);
      float den = 0.f;
      for (int i = 0; i < dn; ++i) den += expf(logit_s[h * 65 + elist[s0 + i]] - mx);
      float inv = 1.f / (den + 1e-16f);
      for (int i = 0; i < dn; ++i) {
        int e = elist[s0 + i];
        logit_s[h * 65 + e] = expf(logit_s[h * 65 + e] - mx) * inv;
      }
    }
  }
  __syncthreads();

  for (int t = tid; t < N_NODES * 8; t += 256) {
    int n = t >> 3, jb = t & 7;
    int j0 = jb * 8;
    float acc[8] = {};
    int s0 = start[n], dn = deg[n];
    for (int i = 0; i < dn; ++i) {
      int e = elist[s0 + i]; int s = sloc[e];
      float al[8];
      #pragma unroll
      for (int h = 0; h < 8; ++h) al[h] = logit_s[h * 65 + e];
      #pragma unroll
      for (int cc = 0; cc < 8; ++cc) {
        int c = j0 + cc;
        float sum = 0.f;
        #pragma unroll
        for (int h = 0; h < 8; ++h) sum += al[h] * xl_s[(h * 64 + c) * N_NODES + s];
        acc[cc] += sum;
      }
    }
    bf16x8 vh, vl;
    #pragma unroll
    for (int cc = 0; cc < 8; ++cc) {
      float v = eluf_(acc[cc] * 0.125f + b_s[j0 + cc]);
      short hb = f2bf(v);
      vh[cc] = hb;
      vl[cc] = f2bf(v - bf2f(hb));
    }
    size_t o = (size_t)(nb + n) * HID + j0;
    *(bf16x8*)(h2hi + o) = vh;
    *(bf16x8*)(h2lo + o) = vl;
  }
}

// ============================================================
// LSTM1 v2: 1024 threads = (gate j, K-half). Each thread holds only 64
// weight floats (16 float4) -> ~90 VGPR, under the 128 cap of 4 waves/SIMD
// (__launch_bounds__(1024,4)) -> no spill (round-4 had VGPR=80 w/ spill,
// 49.7 us). h-reads are wave-uniform broadcasts; partials combined via LDS.
// ============================================================
__global__ __launch_bounds__(1024, 4) void lstm1_kernel(
    const float* __restrict__ X, const float* __restrict__ Whh, float* __restrict__ Y) {
  __shared__ float hs[LSTM1_H], cs[LSTM1_H], part[4 * LSTM1_H], gs[4 * LSTM1_H];
  const int tid = threadIdx.x;
  const int j = tid & 511, half = tid >> 9;   // half in {0,1}
  const int b = blockIdx.x;
  float4 w[16];
  const float4* wp = (const float4*)(Whh + (size_t)j * LSTM1_H + half * 64);
  #pragma unroll
  for (int q = 0; q < 16; ++q) w[q] = wp[q];
  if (tid < LSTM1_H) { hs[tid] = 0.f; cs[tid] = 0.f; }
  __syncthreads();
  for (int t = 0; t < SEQ; ++t) {
    const float* hb = hs + half * 64;   // wave-uniform base -> broadcast reads
    float acc = 0.f;
    #pragma unroll
    for (int q = 0; q < 16; ++q) {
      acc += w[q].x * hb[4 * q] + w[q].y * hb[4 * q + 1]
           + w[q].z * hb[4 * q + 2] + w[q].w * hb[4 * q + 3];
    }
    if (half) part[j] = acc;
    __syncthreads();
    if (!half) gs[j] = acc + part[j] + X[((size_t)b * SEQ + t) * 512 + j];
    __syncthreads();
    if (tid < LSTM1_H) {
      float ig = sigmoidf_(gs[tid]);
      float fg = sigmoidf_(gs[LSTM1_H + tid]);
      float gg = tanhf(gs[2 * LSTM1_H + tid]);
      float og = sigmoidf_(gs[3 * LSTM1_H + tid]);
      float c = fg * cs[tid] + ig * gg;
      cs[tid] = c;
      float h = og * tanhf(c);
      hs[tid] = h;
      Y[((size_t)b * SEQ + t) * LSTM1_H + tid] = h;
    }
    __syncthreads();
  }
}

__global__ __launch_bounds__(256) void x2_kernel(
    const float* __restrict__ Y1, const float* __restrict__ Wih,
    const float* __restrict__ bih, const float* __restrict__ bhh,
    float* __restrict__ X2) {
  __shared__ float ys[LSTM1_H];
  const int g = blockIdx.x, j = threadIdx.x;
  if (j < LSTM1_H) ys[j] = Y1[(size_t)g * LSTM1_H + j];
  __syncthreads();
  const float4* wp = (const float4*)(Wih + (size_t)j * LSTM1_H);
  float acc = bih[j] + bhh[j];
  #pragma unroll
  for (int q = 0; q < 32; ++q) {
    float4 w = wp[q];
    acc += w.x * ys[4 * q] + w.y * ys[4 * q + 1] + w.z * ys[4 * q + 2] + w.w * ys[4 * q + 3];
  }
  X2[(size_t)g * 256 + j] = acc;
}

__global__ __launch_bounds__(256, 2) void lstm2_fc_kernel(
    const float* __restrict__ X, const float* __restrict__ Whh,
    const float* __restrict__ fcW, const float* __restrict__ fcb,
    float* __restrict__ out) {
  __shared__ float hs[LSTM2_H], cs[LSTM2_H], gs[4 * LSTM2_H];
  const int b = blockIdx.x, j = threadIdx.x;
  float4 w[16];
  const float4* wp = (const float4*)(Whh + (size_t)j * LSTM2_H);
  #pragma unroll
  for (int q = 0; q < 16; ++q) w[q] = wp[q];
  if (j < LSTM2_H) { hs[j] = 0.f; cs[j] = 0.f; }
  __syncthreads();
  for (int t = 0; t < SEQ; ++t) {
    float acc = X[((size_t)b * SEQ + t) * 256 + j];
    #pragma unroll
    for (int q = 0; q < 16; ++q) {
      acc += w[q].x * hs[4 * q] + w[q].y * hs[4 * q + 1]
           + w[q].z * hs[4 * q + 2] + w[q].w * hs[4 * q + 3];
    }
    gs[j] = acc;
    __syncthreads();
    if (j < LSTM2_H) {
      float ig = sigmoidf_(gs[j]);
      float fg = sigmoidf_(gs[LSTM2_H + j]);
      float gg = tanhf(gs[2 * LSTM2_H + j]);
      float og = sigmoidf_(gs[3 * LSTM2_H + j]);
      float c = fg * cs[j] + ig * gg;
      cs[j] = c;
      hs[j] = og * tanhf(c);
    }
    __syncthreads();
  }
  if (j < 4) {
    float acc = fcb[j];
    #pragma unroll
    for (int k = 0; k < LSTM2_H; ++k) acc += fcW[j * LSTM2_H + k] * hs[k];
    out[b * 4 + j] = acc;
  }
}

// ============================================================
extern "C" void kernel_launch(void* const* d_in, const int* in_sizes, int n_in,
                              void* d_out, int out_size, void* d_ws, size_t ws_size,
                              hipStream_t stream) {
  const float* x       = (const float*)d_in[0];
  const int*   eidx    = (const int*)d_in[1];
  const float* eattr   = (const float*)d_in[2];
  const float* g1_Wl   = (const float*)d_in[3];
  const float* g1_Wr   = (const float*)d_in[4];
  const float* g1_We   = (const float*)d_in[5];
  const float* g1_att  = (const float*)d_in[6];
  const float* g1_b    = (const float*)d_in[7];
  const float* g2_Wl   = (const float*)d_in[8];
  const float* g2_Wr   = (const float*)d_in[9];
  const float* g2_We   = (const float*)d_in[10];
  const float* g2_att  = (const float*)d_in[11];
  const float* g2_b    = (const float*)d_in[12];
  const float* l1_Wih  = (const float*)d_in[13];
  const float* l1_Whh  = (const float*)d_in[14];
  const float* l1_bih  = (const float*)d_in[15];
  const float* l1_bhh  = (const float*)d_in[16];
  const float* l2_Wih  = (const float*)d_in[17];
  const float* l2_Whh  = (const float*)d_in[18];
  const float* l2_bih  = (const float*)d_in[19];
  const float* l2_bhh  = (const float*)d_in[20];
  const float* fc_W    = (const float*)d_in[21];
  const float* fc_b    = (const float*)d_in[22];
  float* out = (float*)d_out;

  const int* src = eidx;
  const int* dst = eidx + E_EDGES;

  // ---- workspace layout (256B-aligned chunks), peak ~77 MB ----
  char* p = (char*)d_ws;
  auto alloc = [&](size_t bytes) { char* r = p; p += (bytes + 255) & ~(size_t)255; return r; };
  short* h1hi  = (short*)alloc((size_t)CHUNK_N * HC * 2);
  short* h1lo  = (short*)alloc((size_t)CHUNK_N * HC * 2);
  float* xlr2c = (float*)alloc((size_t)CHUNK_N * 1024 * 4);
  short* h2hi  = (short*)alloc((size_t)G_GRAPHS * 2112 * 2);
  short* h2lo  = (short*)alloc((size_t)G_GRAPHS * 2112 * 2);
  short* B2hi  = (short*)alloc((size_t)1024 * 512 * 2);
  short* B2lo  = (short*)alloc((size_t)1024 * 512 * 2);
  short* W1hi  = (short*)alloc((size_t)512 * 2112 * 2);
  short* W1lo  = (short*)alloc((size_t)512 * 2112 * 2);
  float* X1    = (float*)alloc((size_t)G_GRAPHS * 512 * 4);
  float* Y1    = (float*)alloc((size_t)G_GRAPHS * LSTM1_H * 4);
  float* X2    = (float*)alloc((size_t)G_GRAPHS * 256 * 4);
  size_t needed = (size_t)(p - (char*)d_ws);
  if (ws_size < needed) return;   // guard: zero output instead of memory fault

  conv_g2w<<<(1024 * 512) / 256, 256, 0, stream>>>(g2_Wl, g2_Wr, B2hi, B2lo);
  conv_w1<<<(512 * 2112 + 255) / 256, 256, 0, stream>>>(l1_Wih, W1hi, W1lo, 512 * 2112);

  for (int c = 0; c < N_CHUNKS; ++c) {
    int g0 = c * CHUNK_G;
    gat1_kernel<<<CHUNK_G, 256, 0, stream>>>(x, src, dst, eattr, g1_Wl, g1_Wr, g1_We,
                                             g1_att, g1_b, h1hi, h1lo, g0);
    // 64x64 tiles: 2112 blocks (vs 528 at 128^2) for latency hiding
    dim3 grid(1024 / 64, CHUNK_N / 64);
    gemm_mfma<2, 2><<<grid, 256, 0, stream>>>(h1hi, h1lo, B2hi, B2lo, xlr2c,
                                              (const float*)nullptr, (const float*)nullptr,
                                              CHUNK_N, 1024, HC);
    gat2_kernel<<<CHUNK_G, 256, 0, stream>>>(xlr2c, src, dst, eattr, g2_We,
                                             g2_att, g2_b, h2hi, h2lo, g0);
  }

  {
    dim3 grid(512 / 64, G_GRAPHS / 64);
    gemm_mfma<2, 2><<<grid, 256, 0, stream>>>(h2hi, h2lo, W1hi, W1lo, X1,
                                              l1_bih, l1_bhh,
                                              G_GRAPHS, 512, N_NODES * HID);
  }

  lstm1_kernel<<<BATCH, 1024, 0, stream>>>(X1, l1_Whh, Y1);
  x2_kernel<<<G_GRAPHS, 256, 0, stream>>>(Y1, l2_Wih, l2_bih, l2_bhh, X2);
  lstm2_fc_kernel<<<BATCH, 256, 0, stream>>>(X2, l2_Whh, fc_W, fc_b, out);
}